// Round 1
// baseline (3542.491 us; speedup 1.0000x reference)
//
#include <hip/hip_runtime.h>

#define DD   64
#define HIDN 256
#define LLEN 128
#define NSEQ 512

__device__ __forceinline__ float gelu_tanh(float x) {
    float x3 = x * x * x;
    float u = 0.7978845608028654f * (x + 0.044715f * x3);
    return 0.5f * x * (1.0f + tanhf(u));
}

// Gc[s][d][e] = sum_k phi[s][k] * (mp[k][d][e] + (-1)^s * mm[k][d][e])
__global__ __launch_bounds__(256) void gc_kernel(const float* __restrict__ phi,
                                                 const float* __restrict__ mp,
                                                 const float* __restrict__ mm,
                                                 float* __restrict__ Gc) {
    const int s = blockIdx.x;
    const float sg = (s & 1) ? -1.0f : 1.0f;
    float pk[16];
#pragma unroll
    for (int k = 0; k < 16; ++k) pk[k] = phi[s * 16 + k];
    for (int i = threadIdx.x; i < DD * DD; i += 256) {
        float acc = 0.0f;
#pragma unroll
        for (int k = 0; k < 16; ++k)
            acc += pk[k] * (mp[k * (DD * DD) + i] + sg * mm[k * (DD * DD) + i]);
        Gc[s * (DD * DD) + i] = acc;
    }
}

// LayerNorm over d=64 with transpose-gather into sequence-major y[seq][t][d]
__global__ __launch_bounds__(256) void ln_kernel(const float* __restrict__ x,
                                                 float* __restrict__ y,
                                                 const float* __restrict__ gamma,
                                                 const float* __restrict__ beta,
                                                 int rmul, int tmul) {
    const int rowid = blockIdx.x * 4 + (threadIdx.x >> 6);
    const int lane  = threadIdx.x & 63;
    const int seq = rowid >> 7;
    const int t   = rowid & 127;
    const int b = seq >> 7;
    const int r = seq & 127;
    const size_t idx = (size_t)b * 1048576 + (size_t)r * rmul + (size_t)t * tmul + lane;
    float v = x[idx];
    float s1 = v;
#pragma unroll
    for (int m = 32; m >= 1; m >>= 1) s1 += __shfl_xor(s1, m);
    const float mu = s1 * (1.0f / 64.0f);
    const float dv = v - mu;
    float s2 = dv * dv;
#pragma unroll
    for (int m = 32; m >= 1; m >>= 1) s2 += __shfl_xor(s2, m);
    const float rstd = rsqrtf(s2 * (1.0f / 64.0f) + 1e-5f);
    y[(size_t)rowid * 64 + lane] = dv * rstd * gamma[lane] + beta[lane];
}

// spec[seq][l][e] = sum_{t<=l} sum_d y[seq][t][d] * Gc[l-t][d][e]
// One block per sequence. Wave q owns rows l = q + 4*li (li in [0,32)).
__global__ __launch_bounds__(256) void spec_kernel(const float* __restrict__ y,
                                                   const float* __restrict__ Gc,
                                                   float* __restrict__ spec) {
    __shared__ float ys[LLEN * DD];  // 32 KB
    __shared__ float gs[DD * DD];    // 16 KB
    const int seq = blockIdx.x;
    const int tid = threadIdx.x;
    const int q = tid >> 6;
    const int e = tid & 63;

    {
        const float4* ysrc = (const float4*)(y + (size_t)seq * (LLEN * DD));
        float4* ydst = (float4*)ys;
        for (int i = tid; i < LLEN * DD / 4; i += 256) ydst[i] = ysrc[i];
    }

    float acc[32];
#pragma unroll
    for (int i = 0; i < 32; ++i) acc[i] = 0.0f;

    for (int s = 0; s < LLEN; ++s) {
        __syncthreads();  // protect gs readers of iter s-1 (and first ys load)
        {
            const float4* gsrc = (const float4*)(Gc + (size_t)s * (DD * DD));
            float4* gdst = (float4*)gs;
            for (int i = tid; i < DD * DD / 4; i += 256) gdst[i] = gsrc[i];
        }
        __syncthreads();

        int li0 = (s > q) ? ((s - q + 3) >> 2) : 0;
        li0 = __builtin_amdgcn_readfirstlane(li0);  // wave-uniform -> scalar branches
        if (li0 >= 32) continue;

        const float* yb = ys + (q - s) * DD;  // + l*64 gives row t = l - s
#pragma unroll
        for (int d0 = 0; d0 < DD; d0 += 8) {
            const float g0 = gs[(d0 + 0) * DD + e];
            const float g1 = gs[(d0 + 1) * DD + e];
            const float g2 = gs[(d0 + 2) * DD + e];
            const float g3 = gs[(d0 + 3) * DD + e];
            const float g4 = gs[(d0 + 4) * DD + e];
            const float g5 = gs[(d0 + 5) * DD + e];
            const float g6 = gs[(d0 + 6) * DD + e];
            const float g7 = gs[(d0 + 7) * DD + e];
#pragma unroll
            for (int li = 0; li < 32; ++li) {
                if (li >= li0) {
                    const float* yr = yb + (4 * li) * DD + d0;  // row t = q+4li-s
                    acc[li] += yr[0] * g0 + yr[1] * g1 + yr[2] * g2 + yr[3] * g3 +
                               yr[4] * g4 + yr[5] * g5 + yr[6] * g6 + yr[7] * g7;
                }
            }
        }
    }

    float* sp = spec + (size_t)seq * (LLEN * DD);
#pragma unroll
    for (int li = 0; li < 32; ++li) sp[(q + 4 * li) * DD + e] = acc[li];
}

// out[row] = xin[row] + gelu(spec[row] @ w1 + b1) @ w2 + b2
// One block per sequence; w1,w2 staged in LDS (128 KB).
__global__ __launch_bounds__(256) void mlp_kernel(const float* __restrict__ spec,
                                                  const float* __restrict__ xin,
                                                  float* __restrict__ xout,
                                                  const float* __restrict__ w1,
                                                  const float* __restrict__ b1,
                                                  const float* __restrict__ w2,
                                                  const float* __restrict__ b2,
                                                  int rmul, int tmul) {
    __shared__ float w1s[DD * HIDN];    // 64 KB
    __shared__ float w2s[HIDN * DD];    // 64 KB
    const int tid = threadIdx.x;
    const int seq = blockIdx.x;
    for (int i = tid; i < DD * HIDN / 4; i += 256) ((float4*)w1s)[i] = ((const float4*)w1)[i];
    for (int i = tid; i < HIDN * DD / 4; i += 256) ((float4*)w2s)[i] = ((const float4*)w2)[i];
    __syncthreads();

    const int q = tid >> 6, lane = tid & 63;
    const int b = seq >> 7, r = seq & 127;
    const size_t base = (size_t)b * 1048576 + (size_t)r * (size_t)rmul;
    const float b1v0 = b1[lane], b1v1 = b1[64 + lane], b1v2 = b1[128 + lane], b1v3 = b1[192 + lane];
    const float b2v = b2[lane];

    for (int t = q; t < LLEN; t += 4) {
        const float spv = spec[(size_t)seq * (LLEN * DD) + (size_t)t * DD + lane];
        float h0 = b1v0, h1 = b1v1, h2 = b1v2, h3 = b1v3;
#pragma unroll 8
        for (int d = 0; d < DD; ++d) {
            const float sd = __shfl(spv, d);
            const float* wr = w1s + d * HIDN + lane;
            h0 += sd * wr[0];
            h1 += sd * wr[64];
            h2 += sd * wr[128];
            h3 += sd * wr[192];
        }
        h0 = gelu_tanh(h0); h1 = gelu_tanh(h1); h2 = gelu_tanh(h2); h3 = gelu_tanh(h3);

        float o = b2v;
#pragma unroll 8
        for (int j = 0; j < 64; ++j) {
            const float a0 = __shfl(h0, j);
            const float a1 = __shfl(h1, j);
            const float a2 = __shfl(h2, j);
            const float a3 = __shfl(h3, j);
            o += a0 * w2s[(0 * 64 + j) * DD + lane] + a1 * w2s[(1 * 64 + j) * DD + lane] +
                 a2 * w2s[(2 * 64 + j) * DD + lane] + a3 * w2s[(3 * 64 + j) * DD + lane];
        }
        const size_t xi = base + (size_t)t * tmul + lane;
        xout[xi] = xin[xi] + o;
    }
}

extern "C" void kernel_launch(void* const* d_in, const int* in_sizes, int n_in,
                              void* d_out, int out_size, void* d_ws, size_t ws_size,
                              hipStream_t stream) {
    const float* v         = (const float*)d_in[0];
    const float* gamma_row = (const float*)d_in[1];
    const float* beta_row  = (const float*)d_in[2];
    const float* gamma_col = (const float*)d_in[3];
    const float* beta_col  = (const float*)d_in[4];
    const float* mp_row    = (const float*)d_in[5];
    const float* mm_row    = (const float*)d_in[6];
    const float* mp_col    = (const float*)d_in[7];
    const float* mm_col    = (const float*)d_in[8];
    const float* w1_row    = (const float*)d_in[9];
    const float* b1_row    = (const float*)d_in[10];
    const float* w2_row    = (const float*)d_in[11];
    const float* b2_row    = (const float*)d_in[12];
    const float* w1_col    = (const float*)d_in[13];
    const float* b1_col    = (const float*)d_in[14];
    const float* w2_col    = (const float*)d_in[15];
    const float* b2_col    = (const float*)d_in[16];
    const float* phi_row   = (const float*)d_in[17];
    const float* phi_col   = (const float*)d_in[18];
    float* out = (float*)d_out;
    float* ws  = (float*)d_ws;

    float* y    = ws;                   // 4,194,304 floats
    float* spec = ws + 4194304;         // 4,194,304 floats
    float* GcR  = ws + 8388608;         //   524,288 floats
    float* GcC  = ws + 8912896;         //   524,288 floats

    gc_kernel<<<128, 256, 0, stream>>>(phi_row, mp_row, mm_row, GcR);
    gc_kernel<<<128, 256, 0, stream>>>(phi_col, mp_col, mm_col, GcC);

    // row pass: seq=(b,h) r=h (stride 128*64), t=w (stride 64)
    ln_kernel<<<16384, 256, 0, stream>>>(v, y, gamma_row, beta_row, 8192, 64);
    spec_kernel<<<512, 256, 0, stream>>>(y, GcR, spec);
    mlp_kernel<<<512, 256, 0, stream>>>(spec, v, out, w1_row, b1_row, w2_row, b2_row, 8192, 64);

    // col pass: seq=(b,w) r=w (stride 64), t=h (stride 128*64)
    ln_kernel<<<16384, 256, 0, stream>>>(out, y, gamma_col, beta_col, 64, 8192);
    spec_kernel<<<512, 256, 0, stream>>>(y, GcC, spec);
    mlp_kernel<<<512, 256, 0, stream>>>(spec, out, out, w1_col, b1_col, w2_col, b2_col, 64, 8192);
}

// Round 2
// 1050.930 us; speedup vs baseline: 3.3708x; 3.3708x over previous
//
#include <hip/hip_runtime.h>

#define DD   64
#define HIDN 256
#define LLEN 128

typedef __attribute__((ext_vector_type(8))) short bf16x8;
typedef __attribute__((ext_vector_type(4))) float f32x4;

__device__ __forceinline__ float gelu_tanh(float x) {
    float x3 = x * x * x;
    float u = 0.7978845608028654f * (x + 0.044715f * x3);
    return 0.5f * x * (1.0f + tanhf(u));
}

__device__ __forceinline__ unsigned short f2bf(float x) {
    union { float f; unsigned int u; } v; v.f = x;
    unsigned int r = v.u + 0x7FFF + ((v.u >> 16) & 1);
    return (unsigned short)(r >> 16);
}

// Gct[s][e][d] bf16, pre-swizzled: chunk c (8 d's) of row e stored at chunk c^(e&7).
// Gc[s][d][e] = sum_k phi[s][k] * (mp[k][d][e] + (-1)^s * mm[k][d][e])
__global__ __launch_bounds__(256) void gc_kernel(const float* __restrict__ phi,
                                                 const float* __restrict__ mp,
                                                 const float* __restrict__ mm,
                                                 unsigned short* __restrict__ Gct) {
    const int s = blockIdx.x;
    const float sg = (s & 1) ? -1.0f : 1.0f;
    float pk[16];
#pragma unroll
    for (int k = 0; k < 16; ++k) pk[k] = phi[s * 16 + k];
    for (int idx = threadIdx.x; idx < 512; idx += 256) {
        const int e = idx >> 3, c = idx & 7;
        unsigned short h[8];
#pragma unroll
        for (int j = 0; j < 8; ++j) {
            const int d = c * 8 + j;
            float a = 0.0f;
#pragma unroll
            for (int k = 0; k < 16; ++k)
                a += pk[k] * (mp[k * 4096 + d * 64 + e] + sg * mm[k * 4096 + d * 64 + e]);
            h[j] = f2bf(a);
        }
        const int cs = c ^ (e & 7);
        unsigned short* dst = Gct + (size_t)s * 8192 + e * 64 + cs * 8;
#pragma unroll
        for (int j = 0; j < 8; ++j) dst[j] = h[j];
    }
}

// LayerNorm over d=64, transpose-gather into sequence-major bf16 y, pre-swizzled by (t&7)
__global__ __launch_bounds__(256) void ln_kernel(const float* __restrict__ x,
                                                 unsigned short* __restrict__ yb,
                                                 const float* __restrict__ gamma,
                                                 const float* __restrict__ beta,
                                                 int rmul, int tmul) {
    const int rowid = blockIdx.x * 4 + (threadIdx.x >> 6);
    const int lane  = threadIdx.x & 63;
    const int seq = rowid >> 7;
    const int t   = rowid & 127;
    const int b = seq >> 7;
    const int r = seq & 127;
    const size_t idx = (size_t)b * 1048576 + (size_t)r * rmul + (size_t)t * tmul + lane;
    float v = x[idx];
    float s1 = v;
#pragma unroll
    for (int m = 32; m >= 1; m >>= 1) s1 += __shfl_xor(s1, m);
    const float mu = s1 * (1.0f / 64.0f);
    const float dv = v - mu;
    float s2 = dv * dv;
#pragma unroll
    for (int m = 32; m >= 1; m >>= 1) s2 += __shfl_xor(s2, m);
    const float rstd = rsqrtf(s2 * (1.0f / 64.0f) + 1e-5f);
    const float nv = dv * rstd * gamma[lane] + beta[lane];
    const int c = lane >> 3, j = lane & 7;
    yb[(size_t)rowid * 64 + ((c ^ (t & 7)) << 3) + j] = f2bf(nv);
}

// spec[seq][l][e] = sum_{t<=l} sum_d y[seq][t][d] * Gc[l-t][d][e]   via MFMA.
// LDS: ysb rows 0..143 (16 zero-prefix rows), 128B/row, XOR-swizzled chunks; gcs 2 x 64-row slices.
// Wave q owns m-tiles {q, 7-q} (load-balanced), all 4 n-tiles.
__global__ __launch_bounds__(256) void spec_kernel(const unsigned short* __restrict__ yb,
                                                   const unsigned short* __restrict__ Gct,
                                                   float* __restrict__ spec) {
    __shared__ unsigned short lds[17408];  // 0..9215: ysb(144x64), 9216..17407: gcs[2][64x64]
    const int seq = blockIdx.x, tid = threadIdx.x;
    const int q = tid >> 6, lane = tid & 63;
    const int m = lane & 15, g = lane >> 4;
    const int I0 = q, I1 = 7 - q;

    // zero prefix rows 0..15 (2048 B)
    {
        uint2 z; z.x = 0u; z.y = 0u;
        *(uint2*)&lds[tid * 4] = z;
    }
    // stage ysb rows 16..143 (16 KB) via global_load_lds; y is pre-swizzled so linear copy is correct
    {
        const char* ysrc = (const char*)yb + (size_t)seq * 16384 + q * 4096 + lane * 16;
#pragma unroll
        for (int i = 0; i < 4; ++i)
            __builtin_amdgcn_global_load_lds((const void*)(ysrc + i * 1024),
                                             (void*)&lds[1024 + q * 512 * 4 + i * 512], 16, 0, 0);
    }

    // B-operand LDS addresses (constant across s): row = nt*16 + m, chunk = (kk*4+g)^(row&7)
    int bidx[4][2];
#pragma unroll
    for (int nt = 0; nt < 4; ++nt) {
        const int row = nt * 16 + m;
        const int c0 = (g ^ (row & 7)) << 3;
        bidx[nt][0] = 9216 + row * 64 + c0;
        bidx[nt][1] = 9216 + row * 64 + (c0 ^ 32);
    }

    f32x4 acc[2][4];
#pragma unroll
    for (int ii = 0; ii < 2; ++ii)
#pragma unroll
        for (int nt = 0; nt < 4; ++nt) {
            f32x4 z = {0.0f, 0.0f, 0.0f, 0.0f};
            acc[ii][nt] = z;
        }

    for (int sp = 0; sp < 64; ++sp) {
        __syncthreads();  // prior-round gcs readers done (also drains vmcnt incl. ysb loads)
        {
            const char* gsrc = (const char*)Gct + (size_t)sp * 32768 + q * 4096 + lane * 16;
#pragma unroll
            for (int i = 0; i < 4; ++i)
                __builtin_amdgcn_global_load_lds((const void*)(gsrc + i * 1024),
                                                 (void*)&lds[9216 + q * 2048 + i * 512], 16, 0, 0);
        }
        __syncthreads();

#pragma unroll
        for (int h = 0; h < 2; ++h) {
            const int s = 2 * sp + h;
            bf16x8 b[4][2];
#pragma unroll
            for (int nt = 0; nt < 4; ++nt) {
                b[nt][0] = *(const bf16x8*)&lds[bidx[nt][0] + h * 4096];
                b[nt][1] = *(const bf16x8*)&lds[bidx[nt][1] + h * 4096];
            }
            if (s <= I0 * 16 + 15) {
                const int row = 16 + I0 * 16 - s + m;
                const int c0 = (g ^ (row & 7)) << 3;
                const int base = row * 64;
                bf16x8 a0 = *(const bf16x8*)&lds[base + c0];
                bf16x8 a1 = *(const bf16x8*)&lds[base + (c0 ^ 32)];
#pragma unroll
                for (int nt = 0; nt < 4; ++nt) {
                    acc[0][nt] = __builtin_amdgcn_mfma_f32_16x16x32_bf16(a0, b[nt][0], acc[0][nt], 0, 0, 0);
                    acc[0][nt] = __builtin_amdgcn_mfma_f32_16x16x32_bf16(a1, b[nt][1], acc[0][nt], 0, 0, 0);
                }
            }
            if (s <= I1 * 16 + 15) {
                const int row = 16 + I1 * 16 - s + m;
                const int c0 = (g ^ (row & 7)) << 3;
                const int base = row * 64;
                bf16x8 a0 = *(const bf16x8*)&lds[base + c0];
                bf16x8 a1 = *(const bf16x8*)&lds[base + (c0 ^ 32)];
#pragma unroll
                for (int nt = 0; nt < 4; ++nt) {
                    acc[1][nt] = __builtin_amdgcn_mfma_f32_16x16x32_bf16(a0, b[nt][0], acc[1][nt], 0, 0, 0);
                    acc[1][nt] = __builtin_amdgcn_mfma_f32_16x16x32_bf16(a1, b[nt][1], acc[1][nt], 0, 0, 0);
                }
            }
        }
    }

    // C layout: row = 4*g + r, col = m (within 16x16 tile)
    float* sp0 = spec + (size_t)seq * 8192;
#pragma unroll
    for (int ii = 0; ii < 2; ++ii) {
        const int I = ii ? I1 : I0;
#pragma unroll
        for (int nt = 0; nt < 4; ++nt)
#pragma unroll
            for (int r = 0; r < 4; ++r)
                sp0[(I * 16 + 4 * g + r) * 64 + nt * 16 + m] = acc[ii][nt][r];
    }
}

// out[row] = xin[row] + gelu(spec[row] @ w1 + b1) @ w2 + b2
__global__ __launch_bounds__(256) void mlp_kernel(const float* __restrict__ spec,
                                                  const float* __restrict__ xin,
                                                  float* __restrict__ xout,
                                                  const float* __restrict__ w1,
                                                  const float* __restrict__ b1,
                                                  const float* __restrict__ w2,
                                                  const float* __restrict__ b2,
                                                  int rmul, int tmul) {
    __shared__ float w1s[DD * HIDN];    // 64 KB
    __shared__ float w2s[HIDN * DD];    // 64 KB
    const int tid = threadIdx.x;
    const int seq = blockIdx.x;
    for (int i = tid; i < DD * HIDN / 4; i += 256) ((float4*)w1s)[i] = ((const float4*)w1)[i];
    for (int i = tid; i < HIDN * DD / 4; i += 256) ((float4*)w2s)[i] = ((const float4*)w2)[i];
    __syncthreads();

    const int q = tid >> 6, lane = tid & 63;
    const int b = seq >> 7, r = seq & 127;
    const size_t base = (size_t)b * 1048576 + (size_t)r * (size_t)rmul;
    const float b1v0 = b1[lane], b1v1 = b1[64 + lane], b1v2 = b1[128 + lane], b1v3 = b1[192 + lane];
    const float b2v = b2[lane];

    for (int t = q; t < LLEN; t += 4) {
        const float spv = spec[(size_t)seq * (LLEN * DD) + (size_t)t * DD + lane];
        float h0 = b1v0, h1 = b1v1, h2 = b1v2, h3 = b1v3;
#pragma unroll 8
        for (int d = 0; d < DD; ++d) {
            const float sd = __shfl(spv, d);
            const float* wr = w1s + d * HIDN + lane;
            h0 += sd * wr[0];
            h1 += sd * wr[64];
            h2 += sd * wr[128];
            h3 += sd * wr[192];
        }
        h0 = gelu_tanh(h0); h1 = gelu_tanh(h1); h2 = gelu_tanh(h2); h3 = gelu_tanh(h3);

        float o = b2v;
#pragma unroll 8
        for (int j = 0; j < 64; ++j) {
            const float a0 = __shfl(h0, j);
            const float a1 = __shfl(h1, j);
            const float a2 = __shfl(h2, j);
            const float a3 = __shfl(h3, j);
            o += a0 * w2s[(0 * 64 + j) * DD + lane] + a1 * w2s[(1 * 64 + j) * DD + lane] +
                 a2 * w2s[(2 * 64 + j) * DD + lane] + a3 * w2s[(3 * 64 + j) * DD + lane];
        }
        const size_t xi = base + (size_t)t * tmul + lane;
        xout[xi] = xin[xi] + o;
    }
}

extern "C" void kernel_launch(void* const* d_in, const int* in_sizes, int n_in,
                              void* d_out, int out_size, void* d_ws, size_t ws_size,
                              hipStream_t stream) {
    const float* v         = (const float*)d_in[0];
    const float* gamma_row = (const float*)d_in[1];
    const float* beta_row  = (const float*)d_in[2];
    const float* gamma_col = (const float*)d_in[3];
    const float* beta_col  = (const float*)d_in[4];
    const float* mp_row    = (const float*)d_in[5];
    const float* mm_row    = (const float*)d_in[6];
    const float* mp_col    = (const float*)d_in[7];
    const float* mm_col    = (const float*)d_in[8];
    const float* w1_row    = (const float*)d_in[9];
    const float* b1_row    = (const float*)d_in[10];
    const float* w2_row    = (const float*)d_in[11];
    const float* b2_row    = (const float*)d_in[12];
    const float* w1_col    = (const float*)d_in[13];
    const float* b1_col    = (const float*)d_in[14];
    const float* w2_col    = (const float*)d_in[15];
    const float* b2_col    = (const float*)d_in[16];
    const float* phi_row   = (const float*)d_in[17];
    const float* phi_col   = (const float*)d_in[18];
    float* out = (float*)d_out;
    char* ws   = (char*)d_ws;

    unsigned short* yb  = (unsigned short*)ws;                       // 8 MB
    float*          spc = (float*)(ws + (8u << 20));                 // 16 MB
    unsigned short* GcR = (unsigned short*)(ws + (24u << 20));       // 1 MB
    unsigned short* GcC = (unsigned short*)(ws + (25u << 20));       // 1 MB

    gc_kernel<<<128, 256, 0, stream>>>(phi_row, mp_row, mm_row, GcR);
    gc_kernel<<<128, 256, 0, stream>>>(phi_col, mp_col, mm_col, GcC);

    // row pass: seq=(b,h), t=w (stride 64)
    ln_kernel<<<16384, 256, 0, stream>>>(v, yb, gamma_row, beta_row, 8192, 64);
    spec_kernel<<<512, 256, 0, stream>>>(yb, GcR, spc);
    mlp_kernel<<<512, 256, 0, stream>>>(spc, v, out, w1_row, b1_row, w2_row, b2_row, 8192, 64);

    // col pass: seq=(b,w), t=h (stride 128*64)
    ln_kernel<<<16384, 256, 0, stream>>>(out, yb, gamma_col, beta_col, 64, 8192);
    spec_kernel<<<512, 256, 0, stream>>>(yb, GcC, spc);
    mlp_kernel<<<512, 256, 0, stream>>>(spc, out, out, w1_col, b1_col, w2_col, b2_col, 64, 8192);
}

// Round 3
// 304.760 us; speedup vs baseline: 11.6239x; 3.4484x over previous
//
#include <hip/hip_runtime.h>

#define DD   64
#define HIDN 256
#define LLEN 128

typedef __attribute__((ext_vector_type(8))) short bf16x8;
typedef __attribute__((ext_vector_type(4))) float f32x4;

__device__ __forceinline__ float gelu_tanh(float x) {
    float x3 = x * x * x;
    float u = 0.7978845608028654f * (x + 0.044715f * x3);
    return 0.5f * x * (1.0f + tanhf(u));
}

__device__ __forceinline__ unsigned short f2bf(float x) {
    union { float f; unsigned int u; } v; v.f = x;
    unsigned int r = v.u + 0x7FFF + ((v.u >> 16) & 1);
    return (unsigned short)(r >> 16);
}

// Gct[s][e][d] bf16, pre-swizzled: chunk c (8 d's) of row e stored at chunk c^(e&7).
__global__ __launch_bounds__(256) void gc_kernel(const float* __restrict__ phi,
                                                 const float* __restrict__ mp,
                                                 const float* __restrict__ mm,
                                                 unsigned short* __restrict__ Gct) {
    const int s = blockIdx.x;
    const float sg = (s & 1) ? -1.0f : 1.0f;
    float pk[16];
#pragma unroll
    for (int k = 0; k < 16; ++k) pk[k] = phi[s * 16 + k];
    for (int idx = threadIdx.x; idx < 512; idx += 256) {
        const int e = idx >> 3, c = idx & 7;
        unsigned short h[8];
#pragma unroll
        for (int j = 0; j < 8; ++j) {
            const int d = c * 8 + j;
            float a = 0.0f;
#pragma unroll
            for (int k = 0; k < 16; ++k)
                a += pk[k] * (mp[k * 4096 + d * 64 + e] + sg * mm[k * 4096 + d * 64 + e]);
            h[j] = f2bf(a);
        }
        const int cs = c ^ (e & 7);
        unsigned short* dst = Gct + (size_t)s * 8192 + e * 64 + cs * 8;
#pragma unroll
        for (int j = 0; j < 8; ++j) dst[j] = h[j];
    }
}

// Weight prep: w1 [64][256] -> w1t bf16 [256][64] swizzled; w2 [256][64] -> w2t bf16 [64][256] swizzled.
// grid 4: block 0: w1 row, 1: w1 col, 2: w2 row, 3: w2 col
__global__ __launch_bounds__(256) void prep_kernel(const float* __restrict__ w1r, const float* __restrict__ w1c,
                                                   const float* __restrict__ w2r, const float* __restrict__ w2c,
                                                   unsigned short* __restrict__ w1tr, unsigned short* __restrict__ w1tc,
                                                   unsigned short* __restrict__ w2tr, unsigned short* __restrict__ w2tc) {
    const int b = blockIdx.x, tid = threadIdx.x;
    if (b < 2) {
        const float* w1 = b ? w1c : w1r;
        unsigned short* dst = b ? w1tc : w1tr;
        const int n = tid;
#pragma unroll
        for (int c = 0; c < 8; ++c)
#pragma unroll
            for (int j = 0; j < 8; ++j) {
                const int k = c * 8 + j;
                dst[n * 64 + ((c ^ (n & 7)) << 3) + j] = f2bf(w1[k * 256 + n]);
            }
    } else {
        const float* w2 = (b == 3) ? w2c : w2r;
        unsigned short* dst = (b == 3) ? w2tc : w2tr;
        const int n = tid & 63, cq = tid >> 6;
#pragma unroll
        for (int ci = 0; ci < 8; ++ci) {
            const int c = cq * 8 + ci;
#pragma unroll
            for (int j = 0; j < 8; ++j) {
                const int k = c * 8 + j;
                dst[n * 256 + ((c ^ (n & 7)) << 3) + j] = f2bf(w2[k * 64 + n]);
            }
        }
    }
}

// LayerNorm over d=64, transpose-gather into sequence-major bf16 y, pre-swizzled by (t&7)
__global__ __launch_bounds__(256) void ln_kernel(const float* __restrict__ x,
                                                 unsigned short* __restrict__ yb,
                                                 const float* __restrict__ gamma,
                                                 const float* __restrict__ beta,
                                                 int rmul, int tmul) {
    const int rowid = blockIdx.x * 4 + (threadIdx.x >> 6);
    const int lane  = threadIdx.x & 63;
    const int seq = rowid >> 7;
    const int t   = rowid & 127;
    const int b = seq >> 7;
    const int r = seq & 127;
    const size_t idx = (size_t)b * 1048576 + (size_t)r * rmul + (size_t)t * tmul + lane;
    float v = x[idx];
    float s1 = v;
#pragma unroll
    for (int m = 32; m >= 1; m >>= 1) s1 += __shfl_xor(s1, m);
    const float mu = s1 * (1.0f / 64.0f);
    const float dv = v - mu;
    float s2 = dv * dv;
#pragma unroll
    for (int m = 32; m >= 1; m >>= 1) s2 += __shfl_xor(s2, m);
    const float rstd = rsqrtf(s2 * (1.0f / 64.0f) + 1e-5f);
    const float nv = dv * rstd * gamma[lane] + beta[lane];
    const int c = lane >> 3, j = lane & 7;
    yb[(size_t)rowid * 64 + ((c ^ (t & 7)) << 3) + j] = f2bf(nv);
}

// spec[seq][l][e] = sum_{t<=l} sum_d y[seq][t][d] * Gc[l-t][d][e]   via MFMA.
// Output: bf16, pre-swizzled [row][64] (chunk ^ row&7) for mlp's global_load_lds staging.
__global__ __launch_bounds__(256) void spec_kernel(const unsigned short* __restrict__ yb,
                                                   const unsigned short* __restrict__ Gct,
                                                   unsigned short* __restrict__ specb) {
    __shared__ unsigned short lds[17408];  // 0..9215: ysb(144x64), 9216..17407: gcs[2][64x64]
    const int seq = blockIdx.x, tid = threadIdx.x;
    const int q = tid >> 6, lane = tid & 63;
    const int m = lane & 15, g = lane >> 4;
    const int I0 = q, I1 = 7 - q;

    {
        uint2 z; z.x = 0u; z.y = 0u;
        *(uint2*)&lds[tid * 4] = z;
    }
    {
        const char* ysrc = (const char*)yb + (size_t)seq * 16384 + q * 4096 + lane * 16;
#pragma unroll
        for (int i = 0; i < 4; ++i)
            __builtin_amdgcn_global_load_lds((const void*)(ysrc + i * 1024),
                                             (void*)&lds[1024 + q * 2048 + i * 512], 16, 0, 0);
    }

    int bidx[4][2];
#pragma unroll
    for (int nt = 0; nt < 4; ++nt) {
        const int row = nt * 16 + m;
        const int c0 = (g ^ (row & 7)) << 3;
        bidx[nt][0] = 9216 + row * 64 + c0;
        bidx[nt][1] = 9216 + row * 64 + (c0 ^ 32);
    }

    f32x4 acc[2][4];
#pragma unroll
    for (int ii = 0; ii < 2; ++ii)
#pragma unroll
        for (int nt = 0; nt < 4; ++nt) {
            f32x4 z = {0.0f, 0.0f, 0.0f, 0.0f};
            acc[ii][nt] = z;
        }

    for (int sp = 0; sp < 64; ++sp) {
        __syncthreads();
        {
            const char* gsrc = (const char*)Gct + (size_t)sp * 32768 + q * 4096 + lane * 16;
#pragma unroll
            for (int i = 0; i < 4; ++i)
                __builtin_amdgcn_global_load_lds((const void*)(gsrc + i * 1024),
                                                 (void*)&lds[9216 + q * 2048 + i * 512], 16, 0, 0);
        }
        __syncthreads();

#pragma unroll
        for (int h = 0; h < 2; ++h) {
            const int s = 2 * sp + h;
            bf16x8 b[4][2];
#pragma unroll
            for (int nt = 0; nt < 4; ++nt) {
                b[nt][0] = *(const bf16x8*)&lds[bidx[nt][0] + h * 4096];
                b[nt][1] = *(const bf16x8*)&lds[bidx[nt][1] + h * 4096];
            }
            if (s <= I0 * 16 + 15) {
                const int row = 16 + I0 * 16 - s + m;
                const int c0 = (g ^ (row & 7)) << 3;
                const int base = row * 64;
                bf16x8 a0 = *(const bf16x8*)&lds[base + c0];
                bf16x8 a1 = *(const bf16x8*)&lds[base + (c0 ^ 32)];
#pragma unroll
                for (int nt = 0; nt < 4; ++nt) {
                    acc[0][nt] = __builtin_amdgcn_mfma_f32_16x16x32_bf16(a0, b[nt][0], acc[0][nt], 0, 0, 0);
                    acc[0][nt] = __builtin_amdgcn_mfma_f32_16x16x32_bf16(a1, b[nt][1], acc[0][nt], 0, 0, 0);
                }
            }
            if (s <= I1 * 16 + 15) {
                const int row = 16 + I1 * 16 - s + m;
                const int c0 = (g ^ (row & 7)) << 3;
                const int base = row * 64;
                bf16x8 a0 = *(const bf16x8*)&lds[base + c0];
                bf16x8 a1 = *(const bf16x8*)&lds[base + (c0 ^ 32)];
#pragma unroll
                for (int nt = 0; nt < 4; ++nt) {
                    acc[1][nt] = __builtin_amdgcn_mfma_f32_16x16x32_bf16(a0, b[nt][0], acc[1][nt], 0, 0, 0);
                    acc[1][nt] = __builtin_amdgcn_mfma_f32_16x16x32_bf16(a1, b[nt][1], acc[1][nt], 0, 0, 0);
                }
            }
        }
    }

    unsigned short* sp0 = specb + (size_t)seq * 8192;
#pragma unroll
    for (int ii = 0; ii < 2; ++ii) {
        const int I = ii ? I1 : I0;
#pragma unroll
        for (int nt = 0; nt < 4; ++nt)
#pragma unroll
            for (int r = 0; r < 4; ++r) {
                const int row = I * 16 + 4 * g + r;
                const int col = nt * 16 + m;
                const int c = col >> 3, jj = col & 7;
                sp0[row * 64 + (((c ^ (row & 7))) << 3) + jj] = f2bf(acc[ii][nt][r]);
            }
    }
}

// MLP via MFMA: out = xin + gelu(X@W1 + b1)@W2 + b2. One block per sequence (128 rows).
// LDS elems (ushort): X [0,8192); W1T [8192,24576); W2T [24576,40960); H [40960,73728)
#define LX  0
#define LW1 8192
#define LW2 24576
#define LH  40960
__global__ __launch_bounds__(256) void mlp_kernel(const unsigned short* __restrict__ specb,
                                                  const unsigned short* __restrict__ w1t,
                                                  const unsigned short* __restrict__ w2t,
                                                  const float* __restrict__ b1,
                                                  const float* __restrict__ b2,
                                                  const float* __restrict__ xin,
                                                  float* __restrict__ xout,
                                                  int rmul, int tmul) {
    __shared__ unsigned short mld[73728];  // 144 KB
    const int seq = blockIdx.x, tid = threadIdx.x;
    const int q = tid >> 6, lane = tid & 63;
    const int m = lane & 15, g = lane >> 4;

    {
        const char* xsrc = (const char*)specb + (size_t)seq * 16384 + q * 1024 + lane * 16;
#pragma unroll
        for (int i = 0; i < 4; ++i)
            __builtin_amdgcn_global_load_lds((const void*)(xsrc + i * 4096),
                                             (void*)&mld[LX + i * 2048 + q * 512], 16, 0, 0);
        const char* w1src = (const char*)w1t + q * 1024 + lane * 16;
#pragma unroll
        for (int i = 0; i < 8; ++i)
            __builtin_amdgcn_global_load_lds((const void*)(w1src + i * 4096),
                                             (void*)&mld[LW1 + i * 2048 + q * 512], 16, 0, 0);
        const char* w2src = (const char*)w2t + q * 1024 + lane * 16;
#pragma unroll
        for (int i = 0; i < 8; ++i)
            __builtin_amdgcn_global_load_lds((const void*)(w2src + i * 4096),
                                             (void*)&mld[LW2 + i * 2048 + q * 512], 16, 0, 0);
    }
    __syncthreads();

    // ---- GEMM1: H = gelu(X @ W1 + b1), wave q owns hidden cols [64q, 64q+64) ----
    float b1v[4];
#pragma unroll
    for (int nt = 0; nt < 4; ++nt) b1v[nt] = b1[q * 64 + nt * 16 + m];

    f32x4 acc1[8][4];
#pragma unroll
    for (int mt = 0; mt < 8; ++mt)
#pragma unroll
        for (int nt = 0; nt < 4; ++nt) {
            f32x4 z = {b1v[nt], b1v[nt], b1v[nt], b1v[nt]};
            acc1[mt][nt] = z;
        }

    bf16x8 bw1[4][2];
#pragma unroll
    for (int nt = 0; nt < 4; ++nt) {
        const int row = q * 64 + nt * 16 + m;
#pragma unroll
        for (int j = 0; j < 2; ++j)
            bw1[nt][j] = *(const bf16x8*)&mld[LW1 + row * 64 + (((4 * j + g) ^ (row & 7)) << 3)];
    }

#pragma unroll
    for (int mt = 0; mt < 8; ++mt) {
        const int row = mt * 16 + m;
        bf16x8 a0 = *(const bf16x8*)&mld[LX + row * 64 + ((g ^ (row & 7)) << 3)];
        bf16x8 a1 = *(const bf16x8*)&mld[LX + row * 64 + (((4 + g) ^ (row & 7)) << 3)];
#pragma unroll
        for (int nt = 0; nt < 4; ++nt) {
            acc1[mt][nt] = __builtin_amdgcn_mfma_f32_16x16x32_bf16(a0, bw1[nt][0], acc1[mt][nt], 0, 0, 0);
            acc1[mt][nt] = __builtin_amdgcn_mfma_f32_16x16x32_bf16(a1, bw1[nt][1], acc1[mt][nt], 0, 0, 0);
        }
    }

    // gelu + write H bf16 to LDS (swizzled)
#pragma unroll
    for (int mt = 0; mt < 8; ++mt)
#pragma unroll
        for (int nt = 0; nt < 4; ++nt) {
            const int col = q * 64 + nt * 16 + m;
            const int c = col >> 3, jj = col & 7;
#pragma unroll
            for (int r = 0; r < 4; ++r) {
                const int row = mt * 16 + 4 * g + r;
                mld[LH + row * 256 + ((c ^ (row & 7)) << 3) + jj] = f2bf(gelu_tanh(acc1[mt][nt][r]));
            }
        }
    __syncthreads();

    // ---- GEMM2: O = H @ W2 + b2 + xin, wave q owns m-tiles {q, q+4} ----
    float b2v[4];
#pragma unroll
    for (int nt = 0; nt < 4; ++nt) b2v[nt] = b2[nt * 16 + m];

    f32x4 acc2[2][4];
#pragma unroll
    for (int mt = 0; mt < 2; ++mt)
#pragma unroll
        for (int nt = 0; nt < 4; ++nt) {
            f32x4 z = {b2v[nt], b2v[nt], b2v[nt], b2v[nt]};
            acc2[mt][nt] = z;
        }

#pragma unroll
    for (int j = 0; j < 8; ++j) {
        bf16x8 a[2];
#pragma unroll
        for (int mt = 0; mt < 2; ++mt) {
            const int row = (q + 4 * mt) * 16 + m;
            a[mt] = *(const bf16x8*)&mld[LH + row * 256 + (((4 * j + g) ^ (row & 7)) << 3)];
        }
#pragma unroll
        for (int nt = 0; nt < 4; ++nt) {
            const int row = nt * 16 + m;
            bf16x8 bfr = *(const bf16x8*)&mld[LW2 + row * 256 + (((4 * j + g) ^ (row & 7)) << 3)];
            acc2[0][nt] = __builtin_amdgcn_mfma_f32_16x16x32_bf16(a[0], bfr, acc2[0][nt], 0, 0, 0);
            acc2[1][nt] = __builtin_amdgcn_mfma_f32_16x16x32_bf16(a[1], bfr, acc2[1][nt], 0, 0, 0);
        }
    }

    const int b = seq >> 7, rr = seq & 127;
    const size_t base = (size_t)b * 1048576 + (size_t)rr * (size_t)rmul;
#pragma unroll
    for (int mt = 0; mt < 2; ++mt)
#pragma unroll
        for (int nt = 0; nt < 4; ++nt)
#pragma unroll
            for (int r = 0; r < 4; ++r) {
                const int row = (q + 4 * mt) * 16 + 4 * g + r;
                const int col = nt * 16 + m;
                const size_t xi = base + (size_t)row * tmul + col;
                xout[xi] = xin[xi] + acc2[mt][nt][r];
            }
}

extern "C" void kernel_launch(void* const* d_in, const int* in_sizes, int n_in,
                              void* d_out, int out_size, void* d_ws, size_t ws_size,
                              hipStream_t stream) {
    const float* v         = (const float*)d_in[0];
    const float* gamma_row = (const float*)d_in[1];
    const float* beta_row  = (const float*)d_in[2];
    const float* gamma_col = (const float*)d_in[3];
    const float* beta_col  = (const float*)d_in[4];
    const float* mp_row    = (const float*)d_in[5];
    const float* mm_row    = (const float*)d_in[6];
    const float* mp_col    = (const float*)d_in[7];
    const float* mm_col    = (const float*)d_in[8];
    const float* w1_row    = (const float*)d_in[9];
    const float* b1_row    = (const float*)d_in[10];
    const float* w2_row    = (const float*)d_in[11];
    const float* b2_row    = (const float*)d_in[12];
    const float* w1_col    = (const float*)d_in[13];
    const float* b1_col    = (const float*)d_in[14];
    const float* w2_col    = (const float*)d_in[15];
    const float* b2_col    = (const float*)d_in[16];
    const float* phi_row   = (const float*)d_in[17];
    const float* phi_col   = (const float*)d_in[18];
    float* out = (float*)d_out;
    char* ws   = (char*)d_ws;

    unsigned short* yb   = (unsigned short*)ws;                      // 8 MB
    unsigned short* spcb = (unsigned short*)(ws + (8u << 20));       // 8 MB
    unsigned short* GcR  = (unsigned short*)(ws + (16u << 20));      // 1 MB
    unsigned short* GcC  = (unsigned short*)(ws + (17u << 20));      // 1 MB
    unsigned short* w1tR = (unsigned short*)(ws + (18u << 20));
    unsigned short* w2tR = (unsigned short*)(ws + (18u << 20) + 65536);
    unsigned short* w1tC = (unsigned short*)(ws + (18u << 20) + 131072);
    unsigned short* w2tC = (unsigned short*)(ws + (18u << 20) + 196608);

    gc_kernel<<<128, 256, 0, stream>>>(phi_row, mp_row, mm_row, GcR);
    gc_kernel<<<128, 256, 0, stream>>>(phi_col, mp_col, mm_col, GcC);
    prep_kernel<<<4, 256, 0, stream>>>(w1_row, w1_col, w2_row, w2_col, w1tR, w1tC, w2tR, w2tC);

    // row pass: seq=(b,h), t=w (stride 64)
    ln_kernel<<<16384, 256, 0, stream>>>(v, yb, gamma_row, beta_row, 8192, 64);
    spec_kernel<<<512, 256, 0, stream>>>(yb, GcR, spcb);
    mlp_kernel<<<512, 256, 0, stream>>>(spcb, w1tR, w2tR, b1_row, b2_row, v, out, 8192, 64);

    // col pass: seq=(b,w), t=h (stride 128*64)
    ln_kernel<<<16384, 256, 0, stream>>>(out, yb, gamma_col, beta_col, 64, 8192);
    spec_kernel<<<512, 256, 0, stream>>>(yb, GcC, spcb);
    mlp_kernel<<<512, 256, 0, stream>>>(spcb, GcC == GcC ? w1tC : w1tC, w2tC, b1_col, b2_col, out, out, 64, 8192);
}

// Round 4
// 266.569 us; speedup vs baseline: 13.2892x; 1.1433x over previous
//
#include <hip/hip_runtime.h>

#define DD   64
#define HIDN 256
#define LLEN 128

typedef __attribute__((ext_vector_type(8))) short bf16x8;
typedef __attribute__((ext_vector_type(4))) float f32x4;

__device__ __forceinline__ float gelu_fast(float x) {
    // 0.5*x*(1+tanh(u)) == x / (1 + exp(-2u))
    const float u = 0.7978845608028654f * x * (1.0f + 0.044715f * x * x);
    return x * __builtin_amdgcn_rcpf(1.0f + __expf(-2.0f * u));
}

__device__ __forceinline__ unsigned short f2bf(float x) {
    union { float f; unsigned int u; } v; v.f = x;
    unsigned int r = v.u + 0x7FFF + ((v.u >> 16) & 1);
    return (unsigned short)(r >> 16);
}

// Gct[s][e][d] bf16 DENSE (stride 4096 ush/slice), pre-swizzled: chunk c of row e at c^(e&7).
__global__ __launch_bounds__(256) void gc_kernel(const float* __restrict__ phi,
                                                 const float* __restrict__ mp,
                                                 const float* __restrict__ mm,
                                                 unsigned short* __restrict__ Gct) {
    const int s = blockIdx.x;
    const float sg = (s & 1) ? -1.0f : 1.0f;
    float pk[16];
#pragma unroll
    for (int k = 0; k < 16; ++k) pk[k] = phi[s * 16 + k];
    for (int idx = threadIdx.x; idx < 512; idx += 256) {
        const int e = idx >> 3, c = idx & 7;
        unsigned short h[8];
#pragma unroll
        for (int j = 0; j < 8; ++j) {
            const int d = c * 8 + j;
            float a = 0.0f;
#pragma unroll
            for (int k = 0; k < 16; ++k)
                a += pk[k] * (mp[k * 4096 + d * 64 + e] + sg * mm[k * 4096 + d * 64 + e]);
            h[j] = f2bf(a);
        }
        const int cs = c ^ (e & 7);
        unsigned short* dst = Gct + (size_t)s * 4096 + e * 64 + cs * 8;
#pragma unroll
        for (int j = 0; j < 8; ++j) dst[j] = h[j];
    }
}

// Plain bf16 transposes (unswizzled; read straight into registers by mlp):
// w1 [64k][256n] -> w1t [256n][64k]; w2 [256k][64n] -> w2t [64n][256k]
__global__ __launch_bounds__(256) void prep_kernel(const float* __restrict__ w1r, const float* __restrict__ w1c,
                                                   const float* __restrict__ w2r, const float* __restrict__ w2c,
                                                   unsigned short* __restrict__ w1tr, unsigned short* __restrict__ w1tc,
                                                   unsigned short* __restrict__ w2tr, unsigned short* __restrict__ w2tc) {
    const int b = blockIdx.x, tid = threadIdx.x;
    if (b < 2) {
        const float* w1 = b ? w1c : w1r;
        unsigned short* dst = b ? w1tc : w1tr;
        const int n = tid;
        for (int k = 0; k < 64; ++k) dst[n * 64 + k] = f2bf(w1[k * 256 + n]);
    } else {
        const float* w2 = (b == 3) ? w2c : w2r;
        unsigned short* dst = (b == 3) ? w2tc : w2tr;
        const int n = tid & 63, kq = tid >> 6;
        for (int kk = 0; kk < 64; ++kk) {
            const int k = kq * 64 + kk;
            dst[n * 256 + k] = f2bf(w2[k * 64 + n]);
        }
    }
}

// LayerNorm over d=64, transpose-gather into sequence-major bf16 y, pre-swizzled by (t&7)
__global__ __launch_bounds__(256) void ln_kernel(const float* __restrict__ x,
                                                 unsigned short* __restrict__ yb,
                                                 const float* __restrict__ gamma,
                                                 const float* __restrict__ beta,
                                                 int rmul, int tmul) {
    const int rowid = blockIdx.x * 4 + (threadIdx.x >> 6);
    const int lane  = threadIdx.x & 63;
    const int seq = rowid >> 7;
    const int t   = rowid & 127;
    const int b = seq >> 7;
    const int r = seq & 127;
    const size_t idx = (size_t)b * 1048576 + (size_t)r * rmul + (size_t)t * tmul + lane;
    float v = x[idx];
    float s1 = v;
#pragma unroll
    for (int m = 32; m >= 1; m >>= 1) s1 += __shfl_xor(s1, m);
    const float mu = s1 * (1.0f / 64.0f);
    const float dv = v - mu;
    float s2 = dv * dv;
#pragma unroll
    for (int m = 32; m >= 1; m >>= 1) s2 += __shfl_xor(s2, m);
    const float rstd = rsqrtf(s2 * (1.0f / 64.0f) + 1e-5f);
    const float nv = dv * rstd * gamma[lane] + beta[lane];
    const int c = lane >> 3, j = lane & 7;
    yb[(size_t)rowid * 64 + ((c ^ (t & 7)) << 3) + j] = f2bf(nv);
}

// spec[seq][l][e] = sum_{t<=l} sum_d y[t,d] * Gc[l-t,d,e]  via MFMA.
// 2 seqs/block, 4 waves; wave (sl=w>>1, wodd=w&1) owns seq sl, m-tiles {0,2,5,7} or {1,3,4,6}.
// G double-buffered, stage(sp+1) issued before compute(sp), 1 barrier per sp.
// LDS (ush): ys0 [0,9216) ys1 [9216,18432) Gbuf0 [18432,26624) Gbuf1 [26624,34816)
__global__ __launch_bounds__(256) void spec_kernel(const unsigned short* __restrict__ yb,
                                                   const unsigned short* __restrict__ Gct,
                                                   unsigned short* __restrict__ specb) {
    __shared__ unsigned short lds[34816];  // 68 KB
    const int tid = threadIdx.x;
    const int w = tid >> 6, lane = tid & 63;
    const int sl = w >> 1, wodd = w & 1;
    const int seq = blockIdx.x * 2 + sl;
    const int m = lane & 15, g = lane >> 4;
    const int ysb = sl * 9216;

    // zero prefix rows 0..15 of both ys regions
    {
        uint4 z = {0u, 0u, 0u, 0u};
        *(uint4*)((char*)lds + (tid >> 7) * 18432 + (tid & 127) * 16) = z;
    }
    // stage ys (each wave: 8 KB of its seq)
    {
        const char* ysrc = (const char*)yb + (size_t)seq * 16384 + wodd * 8192 + lane * 16;
        char* ydst = (char*)lds + sl * 18432 + 2048 + wodd * 8192;
#pragma unroll
        for (int i = 0; i < 8; ++i)
            __builtin_amdgcn_global_load_lds((const void*)(ysrc + i * 1024),
                                             (void*)(ydst + i * 1024), 16, 0, 0);
    }
    // stage G pair 0 -> buf0
    {
        const char* gsrc = (const char*)Gct + w * 4096 + lane * 16;
        char* gdst = (char*)lds + 36864 + w * 4096;
#pragma unroll
        for (int i = 0; i < 4; ++i)
            __builtin_amdgcn_global_load_lds((const void*)(gsrc + i * 1024),
                                             (void*)(gdst + i * 1024), 16, 0, 0);
    }
    __syncthreads();

    int brel[4];
#pragma unroll
    for (int nt = 0; nt < 4; ++nt) {
        const int row = nt * 16 + m;
        brel[nt] = row * 64 + ((g ^ (row & 7)) << 3);
    }

    f32x4 acc[4][4];
#pragma unroll
    for (int j = 0; j < 4; ++j)
#pragma unroll
        for (int nt = 0; nt < 4; ++nt) {
            f32x4 z = {0.0f, 0.0f, 0.0f, 0.0f};
            acc[j][nt] = z;
        }

    for (int sp = 0; sp < 64; ++sp) {
        const int buf = sp & 1;
        if (sp < 63) {
            const char* gsrc = (const char*)Gct + (size_t)(sp + 1) * 16384 + w * 4096 + lane * 16;
            char* gdst = (char*)lds + 36864 + (buf ^ 1) * 16384 + w * 4096;
#pragma unroll
            for (int i = 0; i < 4; ++i)
                __builtin_amdgcn_global_load_lds((const void*)(gsrc + i * 1024),
                                                 (void*)(gdst + i * 1024), 16, 0, 0);
        }
        const int gbase = 18432 + buf * 8192;
#pragma unroll
        for (int h = 0; h < 2; ++h) {
            const int s = 2 * sp + h;
            const int Gb = gbase + h * 4096;
            bf16x8 b[4][2];
#pragma unroll
            for (int nt = 0; nt < 4; ++nt) {
                b[nt][0] = *(const bf16x8*)&lds[Gb + brel[nt]];
                b[nt][1] = *(const bf16x8*)&lds[Gb + (brel[nt] ^ 32)];
            }
#pragma unroll
            for (int j = 0; j < 4; ++j) {
                const int Ij = 2 * j + ((j & 2) ? (1 - wodd) : wodd);
                if (s <= Ij * 16 + 15) {
                    const int row = 16 + Ij * 16 - s + m;
                    const int c0 = (g ^ (row & 7)) << 3;
                    const int abase = ysb + row * 64;
                    bf16x8 a0 = *(const bf16x8*)&lds[abase + c0];
                    bf16x8 a1 = *(const bf16x8*)&lds[abase + (c0 ^ 32)];
#pragma unroll
                    for (int nt = 0; nt < 4; ++nt) {
                        acc[j][nt] = __builtin_amdgcn_mfma_f32_16x16x32_bf16(a0, b[nt][0], acc[j][nt], 0, 0, 0);
                        acc[j][nt] = __builtin_amdgcn_mfma_f32_16x16x32_bf16(a1, b[nt][1], acc[j][nt], 0, 0, 0);
                    }
                }
            }
        }
        __syncthreads();
    }

    unsigned short* sp0 = specb + (size_t)seq * 8192;
#pragma unroll
    for (int j = 0; j < 4; ++j) {
        const int Ij = 2 * j + ((j & 2) ? (1 - wodd) : wodd);
#pragma unroll
        for (int nt = 0; nt < 4; ++nt)
#pragma unroll
            for (int r = 0; r < 4; ++r) {
                const int row = Ij * 16 + 4 * g + r;
                const int col = nt * 16 + m;
                const int c = col >> 3;
                sp0[row * 64 + ((c ^ (row & 7)) << 3) + (col & 7)] = f2bf(acc[j][nt][r]);
            }
    }
}

// MLP via MFMA: out = xin + gelu(X@W1 + b1)@W2 + b2. One block per sequence.
// LDS (ush): X [0,8192), H [8192,40960)  -> 80 KB, 2 blocks/CU. Weights from L2 into regs.
#define MX 0
#define MH 8192
__global__ __launch_bounds__(256) void mlp_kernel(const unsigned short* __restrict__ specb,
                                                  const unsigned short* __restrict__ w1t,
                                                  const unsigned short* __restrict__ w2t,
                                                  const float* __restrict__ b1,
                                                  const float* __restrict__ b2,
                                                  const float* __restrict__ xin,
                                                  float* __restrict__ xout,
                                                  int rmul, int tmul) {
    __shared__ unsigned short mld[40960];
    const int seq = blockIdx.x, tid = threadIdx.x;
    const int q = tid >> 6, lane = tid & 63;
    const int m = lane & 15, g = lane >> 4;

    {
        const char* xsrc = (const char*)specb + (size_t)seq * 16384 + q * 1024 + lane * 16;
#pragma unroll
        for (int i = 0; i < 4; ++i)
            __builtin_amdgcn_global_load_lds((const void*)(xsrc + i * 4096),
                                             (void*)&mld[MX + i * 2048 + q * 512], 16, 0, 0);
    }
    // W1 B-fragments from global (L2-hot)
    bf16x8 bw1[4][2];
#pragma unroll
    for (int nt = 0; nt < 4; ++nt) {
        const int row = q * 64 + nt * 16 + m;
#pragma unroll
        for (int j = 0; j < 2; ++j)
            bw1[nt][j] = *(const bf16x8*)&w1t[row * 64 + (4 * j + g) * 8];
    }
    float b1v[4];
#pragma unroll
    for (int nt = 0; nt < 4; ++nt) b1v[nt] = b1[q * 64 + nt * 16 + m];
    __syncthreads();  // X staged

    // ---- GEMM1: H = gelu(X @ W1 + b1); wave q owns hidden cols [64q, 64q+64) ----
    f32x4 acc1[8][4];
#pragma unroll
    for (int mt = 0; mt < 8; ++mt)
#pragma unroll
        for (int nt = 0; nt < 4; ++nt) {
            f32x4 z = {b1v[nt], b1v[nt], b1v[nt], b1v[nt]};
            acc1[mt][nt] = z;
        }
#pragma unroll
    for (int mt = 0; mt < 8; ++mt) {
        const int row = mt * 16 + m;
        const int c0 = (g ^ (row & 7)) << 3;
        bf16x8 a0 = *(const bf16x8*)&mld[MX + row * 64 + c0];
        bf16x8 a1 = *(const bf16x8*)&mld[MX + row * 64 + (c0 ^ 32)];
#pragma unroll
        for (int nt = 0; nt < 4; ++nt) {
            acc1[mt][nt] = __builtin_amdgcn_mfma_f32_16x16x32_bf16(a0, bw1[nt][0], acc1[mt][nt], 0, 0, 0);
            acc1[mt][nt] = __builtin_amdgcn_mfma_f32_16x16x32_bf16(a1, bw1[nt][1], acc1[mt][nt], 0, 0, 0);
        }
    }

    // gelu + write H bf16 to LDS (swizzled)
#pragma unroll
    for (int mt = 0; mt < 8; ++mt)
#pragma unroll
        for (int nt = 0; nt < 4; ++nt) {
            const int col = q * 64 + nt * 16 + m;
            const int c = col >> 3, jj = col & 7;
#pragma unroll
            for (int r = 0; r < 4; ++r) {
                const int row = mt * 16 + 4 * g + r;
                mld[MH + row * 256 + ((c ^ (row & 7)) << 3) + jj] = f2bf(gelu_fast(acc1[mt][nt][r]));
            }
        }
    __syncthreads();  // H complete

    // ---- GEMM2: O = H @ W2 + b2 + xin; wave q owns m-tiles {q, q+4} ----
    float b2v[4];
#pragma unroll
    for (int nt = 0; nt < 4; ++nt) b2v[nt] = b2[nt * 16 + m];
    f32x4 acc2[2][4];
#pragma unroll
    for (int mt = 0; mt < 2; ++mt)
#pragma unroll
        for (int nt = 0; nt < 4; ++nt) {
            f32x4 z = {b2v[nt], b2v[nt], b2v[nt], b2v[nt]};
            acc2[mt][nt] = z;
        }
#pragma unroll
    for (int j = 0; j < 8; ++j) {
        bf16x8 a[2];
#pragma unroll
        for (int mt = 0; mt < 2; ++mt) {
            const int row = (q + 4 * mt) * 16 + m;
            a[mt] = *(const bf16x8*)&mld[MH + row * 256 + (((4 * j + g) ^ (row & 7)) << 3)];
        }
#pragma unroll
        for (int nt = 0; nt < 4; ++nt) {
            const int row = nt * 16 + m;
            bf16x8 bfr = *(const bf16x8*)&w2t[row * 256 + (4 * j + g) * 8];
            acc2[0][nt] = __builtin_amdgcn_mfma_f32_16x16x32_bf16(a[0], bfr, acc2[0][nt], 0, 0, 0);
            acc2[1][nt] = __builtin_amdgcn_mfma_f32_16x16x32_bf16(a[1], bfr, acc2[1][nt], 0, 0, 0);
        }
    }

    const int b = seq >> 7, rr = seq & 127;
    const size_t base = (size_t)b * 1048576 + (size_t)rr * (size_t)rmul;
#pragma unroll
    for (int mt = 0; mt < 2; ++mt)
#pragma unroll
        for (int nt = 0; nt < 4; ++nt)
#pragma unroll
            for (int r = 0; r < 4; ++r) {
                const int row = (q + 4 * mt) * 16 + 4 * g + r;
                const int col = nt * 16 + m;
                const size_t xi = base + (size_t)row * tmul + col;
                xout[xi] = xin[xi] + acc2[mt][nt][r];
            }
}

extern "C" void kernel_launch(void* const* d_in, const int* in_sizes, int n_in,
                              void* d_out, int out_size, void* d_ws, size_t ws_size,
                              hipStream_t stream) {
    const float* v         = (const float*)d_in[0];
    const float* gamma_row = (const float*)d_in[1];
    const float* beta_row  = (const float*)d_in[2];
    const float* gamma_col = (const float*)d_in[3];
    const float* beta_col  = (const float*)d_in[4];
    const float* mp_row    = (const float*)d_in[5];
    const float* mm_row    = (const float*)d_in[6];
    const float* mp_col    = (const float*)d_in[7];
    const float* mm_col    = (const float*)d_in[8];
    const float* w1_row    = (const float*)d_in[9];
    const float* b1_row    = (const float*)d_in[10];
    const float* w2_row    = (const float*)d_in[11];
    const float* b2_row    = (const float*)d_in[12];
    const float* w1_col    = (const float*)d_in[13];
    const float* b1_col    = (const float*)d_in[14];
    const float* w2_col    = (const float*)d_in[15];
    const float* b2_col    = (const float*)d_in[16];
    const float* phi_row   = (const float*)d_in[17];
    const float* phi_col   = (const float*)d_in[18];
    float* out = (float*)d_out;
    char* ws   = (char*)d_ws;

    unsigned short* yb   = (unsigned short*)ws;                      // 8 MB
    unsigned short* spcb = (unsigned short*)(ws + (8u << 20));       // 8 MB
    unsigned short* GcR  = (unsigned short*)(ws + (16u << 20));      // 1 MB
    unsigned short* GcC  = (unsigned short*)(ws + (17u << 20));      // 1 MB
    unsigned short* w1tR = (unsigned short*)(ws + (18u << 20));
    unsigned short* w2tR = (unsigned short*)(ws + (18u << 20) + 32768);
    unsigned short* w1tC = (unsigned short*)(ws + (18u << 20) + 65536);
    unsigned short* w2tC = (unsigned short*)(ws + (18u << 20) + 98304);

    gc_kernel<<<128, 256, 0, stream>>>(phi_row, mp_row, mm_row, GcR);
    gc_kernel<<<128, 256, 0, stream>>>(phi_col, mp_col, mm_col, GcC);
    prep_kernel<<<4, 256, 0, stream>>>(w1_row, w1_col, w2_row, w2_col, w1tR, w1tC, w2tR, w2tC);

    // row pass: seq=(b,h), t=w (stride 64)
    ln_kernel<<<16384, 256, 0, stream>>>(v, yb, gamma_row, beta_row, 8192, 64);
    spec_kernel<<<256, 256, 0, stream>>>(yb, GcR, spcb);
    mlp_kernel<<<512, 256, 0, stream>>>(spcb, w1tR, w2tR, b1_row, b2_row, v, out, 8192, 64);

    // col pass: seq=(b,w), t=h (stride 128*64)
    ln_kernel<<<16384, 256, 0, stream>>>(out, yb, gamma_col, beta_col, 64, 8192);
    spec_kernel<<<256, 256, 0, stream>>>(yb, GcC, spcb);
    mlp_kernel<<<512, 256, 0, stream>>>(spcb, w1tC, w2tC, b1_col, b2_col, out, out, 64, 8192);
}

// Round 5
// 225.006 us; speedup vs baseline: 15.7440x; 1.1847x over previous
//
#include <hip/hip_runtime.h>

#define DD   64
#define HIDN 256
#define LLEN 128

typedef __attribute__((ext_vector_type(8))) short bf16x8;
typedef __attribute__((ext_vector_type(4))) float f32x4;

__device__ __forceinline__ float gelu_fast(float x) {
    const float u = 0.7978845608028654f * x * (1.0f + 0.044715f * x * x);
    return x * __builtin_amdgcn_rcpf(1.0f + __expf(-2.0f * u));
}

__device__ __forceinline__ unsigned short f2bf(float x) {
    union { float f; unsigned int u; } v; v.f = x;
    unsigned int r = v.u + 0x7FFF + ((v.u >> 16) & 1);
    return (unsigned short)(r >> 16);
}

// Gct[s][e][d] bf16 DENSE (4096 ush/slice), pre-swizzled: chunk c of row e at c^(e&7).
__device__ __forceinline__ void gc_body(int s, int tid,
                                        const float* __restrict__ phi,
                                        const float* __restrict__ mp,
                                        const float* __restrict__ mm,
                                        unsigned short* __restrict__ Gct) {
    const float sg = (s & 1) ? -1.0f : 1.0f;
    float pk[16];
#pragma unroll
    for (int k = 0; k < 16; ++k) pk[k] = phi[s * 16 + k];
    for (int idx = tid; idx < 512; idx += 256) {
        const int e = idx >> 3, c = idx & 7;
        unsigned short h[8];
#pragma unroll
        for (int j = 0; j < 8; ++j) {
            const int d = c * 8 + j;
            float a = 0.0f;
#pragma unroll
            for (int k = 0; k < 16; ++k)
                a += pk[k] * (mp[k * 4096 + d * 64 + e] + sg * mm[k * 4096 + d * 64 + e]);
            h[j] = f2bf(a);
        }
        const int cs = c ^ (e & 7);
        unsigned short* dst = Gct + (size_t)s * 4096 + e * 64 + cs * 8;
#pragma unroll
        for (int j = 0; j < 8; ++j) dst[j] = h[j];
    }
}

// blocks 0..127: Gc row; 128..255: Gc col; 256..259: weight transposes
__global__ __launch_bounds__(256) void init_kernel(const float* __restrict__ phi_r, const float* __restrict__ mp_r,
                                                   const float* __restrict__ mm_r, unsigned short* __restrict__ GcR,
                                                   const float* __restrict__ phi_c, const float* __restrict__ mp_c,
                                                   const float* __restrict__ mm_c, unsigned short* __restrict__ GcC,
                                                   const float* __restrict__ w1r, const float* __restrict__ w1c,
                                                   const float* __restrict__ w2r, const float* __restrict__ w2c,
                                                   unsigned short* __restrict__ w1tr, unsigned short* __restrict__ w1tc,
                                                   unsigned short* __restrict__ w2tr, unsigned short* __restrict__ w2tc) {
    const int bid = blockIdx.x, tid = threadIdx.x;
    if (bid < 128) {
        gc_body(bid, tid, phi_r, mp_r, mm_r, GcR);
    } else if (bid < 256) {
        gc_body(bid - 128, tid, phi_c, mp_c, mm_c, GcC);
    } else {
        const int b = bid - 256;
        if (b < 2) {
            const float* w1 = b ? w1c : w1r;
            unsigned short* dst = b ? w1tc : w1tr;
            const int n = tid;
            for (int k = 0; k < 64; ++k) dst[n * 64 + k] = f2bf(w1[k * 256 + n]);
        } else {
            const float* w2 = (b == 3) ? w2c : w2r;
            unsigned short* dst = (b == 3) ? w2tc : w2tr;
            const int n = tid & 63, kq = tid >> 6;
            for (int kk = 0; kk < 64; ++kk) {
                const int k = kq * 64 + kk;
                dst[n * 256 + k] = f2bf(w2[k * 64 + n]);
            }
        }
    }
}

// LayerNorm over d=64, transpose-gather into sequence-major bf16 y, pre-swizzled by (t&7)
__global__ __launch_bounds__(256) void ln_kernel(const float* __restrict__ x,
                                                 unsigned short* __restrict__ yb,
                                                 const float* __restrict__ gamma,
                                                 const float* __restrict__ beta,
                                                 int rmul, int tmul) {
    const int rowid = blockIdx.x * 4 + (threadIdx.x >> 6);
    const int lane  = threadIdx.x & 63;
    const int seq = rowid >> 7;
    const int t   = rowid & 127;
    const int b = seq >> 7;
    const int r = seq & 127;
    const size_t idx = (size_t)b * 1048576 + (size_t)r * rmul + (size_t)t * tmul + lane;
    float v = x[idx];
    float s1 = v;
#pragma unroll
    for (int m = 32; m >= 1; m >>= 1) s1 += __shfl_xor(s1, m);
    const float mu = s1 * (1.0f / 64.0f);
    const float dv = v - mu;
    float s2 = dv * dv;
#pragma unroll
    for (int m = 32; m >= 1; m >>= 1) s2 += __shfl_xor(s2, m);
    const float rstd = rsqrtf(s2 * (1.0f / 64.0f) + 1e-5f);
    const float nv = dv * rstd * gamma[lane] + beta[lane];
    const int c = lane >> 3, j = lane & 7;
    yb[(size_t)rowid * 64 + ((c ^ (t & 7)) << 3) + j] = f2bf(nv);
}

// spec[seq][l][e] = sum_{t<=l} sum_d y[t,d] * Gc[l-t,d,e]  via MFMA.
// 2 seqs/block, 4 waves; wave (sl=w>>1, wodd=w&1) owns seq sl, m-tiles {0,2,5,7}/{1,3,4,6}.
// G-pairs QUAD-buffered; stage(sp+3) issued AFTER barrier sp (WAR-safe); counted vmcnt(8),
// raw s_barrier, no drain-to-0 in the main loop (T3/T4).
// LDS (ush): ys0 [0,9216) ys1 [9216,18432) Gbuf[p] at 18432 + p*8192, p=0..3  -> 100 KB
__global__ __launch_bounds__(256) void spec_kernel(const unsigned short* __restrict__ yb,
                                                   const unsigned short* __restrict__ Gct,
                                                   unsigned short* __restrict__ specb) {
    __shared__ unsigned short lds[51200];  // 100 KB
    const int tid = threadIdx.x;
    const int w = tid >> 6, lane = tid & 63;
    const int sl = w >> 1, wodd = w & 1;
    const int seq = blockIdx.x * 2 + sl;
    const int m = lane & 15, g = lane >> 4;
    const int ysb = sl * 9216;

    // zero prefix rows 0..15 of both ys regions (ds_write, covered by lgkmcnt(0) at sp=0)
    {
        uint4 z = {0u, 0u, 0u, 0u};
        *(uint4*)((char*)lds + (tid >> 7) * 18432 + (tid & 127) * 16) = z;
    }
    // stage ys rows 16..143 (each wave 8 KB of its seq)
    {
        const char* ysrc = (const char*)yb + (size_t)seq * 16384 + wodd * 8192 + lane * 16;
        char* ydst = (char*)lds + sl * 18432 + 2048 + wodd * 8192;
#pragma unroll
        for (int i = 0; i < 8; ++i)
            __builtin_amdgcn_global_load_lds((const void*)(ysrc + i * 1024),
                                             (void*)(ydst + i * 1024), 16, 0, 0);
    }
    // prologue: stage G pairs 0,1,2
#pragma unroll
    for (int p = 0; p < 3; ++p) {
        const char* gsrc = (const char*)Gct + (size_t)p * 16384 + w * 4096 + lane * 16;
        char* gdst = (char*)lds + 36864 + p * 16384 + w * 4096;
#pragma unroll
        for (int i = 0; i < 4; ++i)
            __builtin_amdgcn_global_load_lds((const void*)(gsrc + i * 1024),
                                             (void*)(gdst + i * 1024), 16, 0, 0);
    }

    int brel[4];
#pragma unroll
    for (int nt = 0; nt < 4; ++nt) {
        const int row = nt * 16 + m;
        brel[nt] = row * 64 + ((g ^ (row & 7)) << 3);
    }

    f32x4 acc[4][4];
#pragma unroll
    for (int j = 0; j < 4; ++j)
#pragma unroll
        for (int nt = 0; nt < 4; ++nt) {
            f32x4 z = {0.0f, 0.0f, 0.0f, 0.0f};
            acc[j][nt] = z;
        }

    for (int sp = 0; sp < 64; ++sp) {
        // wait: pair sp landed (keep pairs sp+1, sp+2 in flight = 8 loads)
        if (sp == 0)       asm volatile("s_waitcnt vmcnt(8) lgkmcnt(0)" ::: "memory");
        else if (sp < 62)  asm volatile("s_waitcnt vmcnt(8)" ::: "memory");
        else if (sp == 62) asm volatile("s_waitcnt vmcnt(4)" ::: "memory");
        else               asm volatile("s_waitcnt vmcnt(0)" ::: "memory");
        __builtin_amdgcn_s_barrier();
        __builtin_amdgcn_sched_barrier(0);

        // issue stage(sp+3): after the barrier, so every wave has finished pair sp-1
        // (which shares buffer (sp+3)&3) -> WAR-safe with 4 buffers.
        if (sp < 61) {
            const int p = sp + 3;
            const char* gsrc = (const char*)Gct + (size_t)p * 16384 + w * 4096 + lane * 16;
            char* gdst = (char*)lds + 36864 + (p & 3) * 16384 + w * 4096;
#pragma unroll
            for (int i = 0; i < 4; ++i)
                __builtin_amdgcn_global_load_lds((const void*)(gsrc + i * 1024),
                                                 (void*)(gdst + i * 1024), 16, 0, 0);
        }

        const int gbase = 18432 + (sp & 3) * 8192;
#pragma unroll
        for (int h = 0; h < 2; ++h) {
            const int s = 2 * sp + h;
            const int Gb = gbase + h * 4096;
            bf16x8 b[4][2];
#pragma unroll
            for (int nt = 0; nt < 4; ++nt) {
                b[nt][0] = *(const bf16x8*)&lds[Gb + brel[nt]];
                b[nt][1] = *(const bf16x8*)&lds[Gb + (brel[nt] ^ 32)];
            }
#pragma unroll
            for (int j = 0; j < 4; ++j) {
                const int Ij = 2 * j + ((j & 2) ? (1 - wodd) : wodd);
                if (s <= Ij * 16 + 15) {
                    const int row = 16 + Ij * 16 - s + m;
                    const int c0 = (g ^ (row & 7)) << 3;
                    const int abase = ysb + row * 64;
                    bf16x8 a0 = *(const bf16x8*)&lds[abase + c0];
                    bf16x8 a1 = *(const bf16x8*)&lds[abase + (c0 ^ 32)];
#pragma unroll
                    for (int nt = 0; nt < 4; ++nt) {
                        acc[j][nt] = __builtin_amdgcn_mfma_f32_16x16x32_bf16(a0, b[nt][0], acc[j][nt], 0, 0, 0);
                        acc[j][nt] = __builtin_amdgcn_mfma_f32_16x16x32_bf16(a1, b[nt][1], acc[j][nt], 0, 0, 0);
                    }
                }
            }
        }
    }

    unsigned short* sp0 = specb + (size_t)seq * 8192;
#pragma unroll
    for (int j = 0; j < 4; ++j) {
        const int Ij = 2 * j + ((j & 2) ? (1 - wodd) : wodd);
#pragma unroll
        for (int nt = 0; nt < 4; ++nt)
#pragma unroll
            for (int r = 0; r < 4; ++r) {
                const int row = Ij * 16 + 4 * g + r;
                const int col = nt * 16 + m;
                const int c = col >> 3;
                sp0[row * 64 + ((c ^ (row & 7)) << 3) + (col & 7)] = f2bf(acc[j][nt][r]);
            }
    }
}

// MLP via MFMA: out = xin + gelu(X@W1 + b1)@W2 + b2. One block per sequence.
// LDS (ush): X [0,8192), H [8192,40960) -> 80 KB, 2 blocks/CU. Weights from L2 into regs.
#define MX 0
#define MH 8192
__global__ __launch_bounds__(256) void mlp_kernel(const unsigned short* __restrict__ specb,
                                                  const unsigned short* __restrict__ w1t,
                                                  const unsigned short* __restrict__ w2t,
                                                  const float* __restrict__ b1,
                                                  const float* __restrict__ b2,
                                                  const float* __restrict__ xin,
                                                  float* __restrict__ xout,
                                                  int rmul, int tmul) {
    __shared__ unsigned short mld[40960];
    const int seq = blockIdx.x, tid = threadIdx.x;
    const int q = tid >> 6, lane = tid & 63;
    const int m = lane & 15, g = lane >> 4;

    {
        const char* xsrc = (const char*)specb + (size_t)seq * 16384 + q * 1024 + lane * 16;
#pragma unroll
        for (int i = 0; i < 4; ++i)
            __builtin_amdgcn_global_load_lds((const void*)(xsrc + i * 4096),
                                             (void*)&mld[MX + i * 2048 + q * 512], 16, 0, 0);
    }
    bf16x8 bw1[4][2];
#pragma unroll
    for (int nt = 0; nt < 4; ++nt) {
        const int row = q * 64 + nt * 16 + m;
#pragma unroll
        for (int j = 0; j < 2; ++j)
            bw1[nt][j] = *(const bf16x8*)&w1t[row * 64 + (4 * j + g) * 8];
    }
    float b1v[4];
#pragma unroll
    for (int nt = 0; nt < 4; ++nt) b1v[nt] = b1[q * 64 + nt * 16 + m];
    __syncthreads();  // X staged

    f32x4 acc1[8][4];
#pragma unroll
    for (int mt = 0; mt < 8; ++mt)
#pragma unroll
        for (int nt = 0; nt < 4; ++nt) {
            f32x4 z = {b1v[nt], b1v[nt], b1v[nt], b1v[nt]};
            acc1[mt][nt] = z;
        }
#pragma unroll
    for (int mt = 0; mt < 8; ++mt) {
        const int row = mt * 16 + m;
        const int c0 = (g ^ (row & 7)) << 3;
        bf16x8 a0 = *(const bf16x8*)&mld[MX + row * 64 + c0];
        bf16x8 a1 = *(const bf16x8*)&mld[MX + row * 64 + (c0 ^ 32)];
#pragma unroll
        for (int nt = 0; nt < 4; ++nt) {
            acc1[mt][nt] = __builtin_amdgcn_mfma_f32_16x16x32_bf16(a0, bw1[nt][0], acc1[mt][nt], 0, 0, 0);
            acc1[mt][nt] = __builtin_amdgcn_mfma_f32_16x16x32_bf16(a1, bw1[nt][1], acc1[mt][nt], 0, 0, 0);
        }
    }

#pragma unroll
    for (int mt = 0; mt < 8; ++mt)
#pragma unroll
        for (int nt = 0; nt < 4; ++nt) {
            const int col = q * 64 + nt * 16 + m;
            const int c = col >> 3, jj = col & 7;
#pragma unroll
            for (int r = 0; r < 4; ++r) {
                const int row = mt * 16 + 4 * g + r;
                mld[MH + row * 256 + ((c ^ (row & 7)) << 3) + jj] = f2bf(gelu_fast(acc1[mt][nt][r]));
            }
        }
    __syncthreads();  // H complete

    float b2v[4];
#pragma unroll
    for (int nt = 0; nt < 4; ++nt) b2v[nt] = b2[nt * 16 + m];
    f32x4 acc2[2][4];
#pragma unroll
    for (int mt = 0; mt < 2; ++mt)
#pragma unroll
        for (int nt = 0; nt < 4; ++nt) {
            f32x4 z = {b2v[nt], b2v[nt], b2v[nt], b2v[nt]};
            acc2[mt][nt] = z;
        }
#pragma unroll
    for (int j = 0; j < 8; ++j) {
        bf16x8 a[2];
#pragma unroll
        for (int mt = 0; mt < 2; ++mt) {
            const int row = (q + 4 * mt) * 16 + m;
            a[mt] = *(const bf16x8*)&mld[MH + row * 256 + (((4 * j + g) ^ (row & 7)) << 3)];
        }
#pragma unroll
        for (int nt = 0; nt < 4; ++nt) {
            const int row = nt * 16 + m;
            bf16x8 bfr = *(const bf16x8*)&w2t[row * 256 + (4 * j + g) * 8];
            acc2[0][nt] = __builtin_amdgcn_mfma_f32_16x16x32_bf16(a[0], bfr, acc2[0][nt], 0, 0, 0);
            acc2[1][nt] = __builtin_amdgcn_mfma_f32_16x16x32_bf16(a[1], bfr, acc2[1][nt], 0, 0, 0);
        }
    }

    const int b = seq >> 7, rr = seq & 127;
    const size_t base = (size_t)b * 1048576 + (size_t)rr * (size_t)rmul;
#pragma unroll
    for (int mt = 0; mt < 2; ++mt)
#pragma unroll
        for (int nt = 0; nt < 4; ++nt)
#pragma unroll
            for (int r = 0; r < 4; ++r) {
                const int row = (q + 4 * mt) * 16 + 4 * g + r;
                const int col = nt * 16 + m;
                const size_t xi = base + (size_t)row * tmul + col;
                xout[xi] = xin[xi] + acc2[mt][nt][r];
            }
}

extern "C" void kernel_launch(void* const* d_in, const int* in_sizes, int n_in,
                              void* d_out, int out_size, void* d_ws, size_t ws_size,
                              hipStream_t stream) {
    const float* v         = (const float*)d_in[0];
    const float* gamma_row = (const float*)d_in[1];
    const float* beta_row  = (const float*)d_in[2];
    const float* gamma_col = (const float*)d_in[3];
    const float* beta_col  = (const float*)d_in[4];
    const float* mp_row    = (const float*)d_in[5];
    const float* mm_row    = (const float*)d_in[6];
    const float* mp_col    = (const float*)d_in[7];
    const float* mm_col    = (const float*)d_in[8];
    const float* w1_row    = (const float*)d_in[9];
    const float* b1_row    = (const float*)d_in[10];
    const float* w2_row    = (const float*)d_in[11];
    const float* b2_row    = (const float*)d_in[12];
    const float* w1_col    = (const float*)d_in[13];
    const float* b1_col    = (const float*)d_in[14];
    const float* w2_col    = (const float*)d_in[15];
    const float* b2_col    = (const float*)d_in[16];
    const float* phi_row   = (const float*)d_in[17];
    const float* phi_col   = (const float*)d_in[18];
    float* out = (float*)d_out;
    char* ws   = (char*)d_ws;

    unsigned short* yb   = (unsigned short*)ws;                      // 8 MB
    unsigned short* spcb = (unsigned short*)(ws + (8u << 20));       // 8 MB
    unsigned short* GcR  = (unsigned short*)(ws + (16u << 20));      // 1 MB
    unsigned short* GcC  = (unsigned short*)(ws + (17u << 20));      // 1 MB
    unsigned short* w1tR = (unsigned short*)(ws + (18u << 20));
    unsigned short* w2tR = (unsigned short*)(ws + (18u << 20) + 32768);
    unsigned short* w1tC = (unsigned short*)(ws + (18u << 20) + 65536);
    unsigned short* w2tC = (unsigned short*)(ws + (18u << 20) + 98304);

    init_kernel<<<260, 256, 0, stream>>>(phi_row, mp_row, mm_row, GcR,
                                         phi_col, mp_col, mm_col, GcC,
                                         w1_row, w1_col, w2_row, w2_col,
                                         w1tR, w1tC, w2tR, w2tC);

    // row pass: seq=(b,h), t=w (stride 64)
    ln_kernel<<<16384, 256, 0, stream>>>(v, yb, gamma_row, beta_row, 8192, 64);
    spec_kernel<<<256, 256, 0, stream>>>(yb, GcR, spcb);
    mlp_kernel<<<512, 256, 0, stream>>>(spcb, w1tR, w2tR, b1_row, b2_row, v, out, 8192, 64);

    // col pass: seq=(b,w), t=h (stride 128*64)
    ln_kernel<<<16384, 256, 0, stream>>>(out, yb, gamma_col, beta_col, 64, 8192);
    spec_kernel<<<256, 256, 0, stream>>>(yb, GcC, spcb);
    mlp_kernel<<<512, 256, 0, stream>>>(spcb, w1tC, w2tC, b1_col, b2_col, out, out, 64, 8192);
}

// Round 6
// 196.913 us; speedup vs baseline: 17.9901x; 1.1427x over previous
//
#include <hip/hip_runtime.h>

#define DD   64
#define HIDN 256
#define LLEN 128

typedef __attribute__((ext_vector_type(8))) short bf16x8;
typedef __attribute__((ext_vector_type(4))) float f32x4;

__device__ __forceinline__ float gelu_fast(float x) {
    const float u = 0.7978845608028654f * x * (1.0f + 0.044715f * x * x);
    return x * __builtin_amdgcn_rcpf(1.0f + __expf(-2.0f * u));
}

__device__ __forceinline__ unsigned short f2bf(float x) {
    union { float f; unsigned int u; } v; v.f = x;
    unsigned int r = v.u + 0x7FFF + ((v.u >> 16) & 1);
    return (unsigned short)(r >> 16);
}

// Gct[s][e][d] bf16 DENSE (4096 ush/slice), pre-swizzled: chunk c of row e at c^(e&7).
__device__ __forceinline__ void gc_body(int s, int tid,
                                        const float* __restrict__ phi,
                                        const float* __restrict__ mp,
                                        const float* __restrict__ mm,
                                        unsigned short* __restrict__ Gct) {
    const float sg = (s & 1) ? -1.0f : 1.0f;
    float pk[16];
#pragma unroll
    for (int k = 0; k < 16; ++k) pk[k] = phi[s * 16 + k];
    for (int idx = tid; idx < 512; idx += 256) {
        const int e = idx >> 3, c = idx & 7;
        unsigned short h[8];
#pragma unroll
        for (int j = 0; j < 8; ++j) {
            const int d = c * 8 + j;
            float a = 0.0f;
#pragma unroll
            for (int k = 0; k < 16; ++k)
                a += pk[k] * (mp[k * 4096 + d * 64 + e] + sg * mm[k * 4096 + d * 64 + e]);
            h[j] = f2bf(a);
        }
        const int cs = c ^ (e & 7);
        unsigned short* dst = Gct + (size_t)s * 4096 + e * 64 + cs * 8;
#pragma unroll
        for (int j = 0; j < 8; ++j) dst[j] = h[j];
    }
}

// blocks 0..127: Gc row; 128..255: Gc col; 256..259: weight transposes
__global__ __launch_bounds__(256) void init_kernel(const float* __restrict__ phi_r, const float* __restrict__ mp_r,
                                                   const float* __restrict__ mm_r, unsigned short* __restrict__ GcR,
                                                   const float* __restrict__ phi_c, const float* __restrict__ mp_c,
                                                   const float* __restrict__ mm_c, unsigned short* __restrict__ GcC,
                                                   const float* __restrict__ w1r, const float* __restrict__ w1c,
                                                   const float* __restrict__ w2r, const float* __restrict__ w2c,
                                                   unsigned short* __restrict__ w1tr, unsigned short* __restrict__ w1tc,
                                                   unsigned short* __restrict__ w2tr, unsigned short* __restrict__ w2tc) {
    const int bid = blockIdx.x, tid = threadIdx.x;
    if (bid < 128) {
        gc_body(bid, tid, phi_r, mp_r, mm_r, GcR);
    } else if (bid < 256) {
        gc_body(bid - 128, tid, phi_c, mp_c, mm_c, GcC);
    } else {
        const int b = bid - 256;
        if (b < 2) {
            const float* w1 = b ? w1c : w1r;
            unsigned short* dst = b ? w1tc : w1tr;
            const int n = tid;
            for (int k = 0; k < 64; ++k) dst[n * 64 + k] = f2bf(w1[k * 256 + n]);
        } else {
            const float* w2 = (b == 3) ? w2c : w2r;
            unsigned short* dst = (b == 3) ? w2tc : w2tr;
            const int n = tid & 63, kq = tid >> 6;
            for (int kk = 0; kk < 64; ++kk) {
                const int k = kq * 64 + kk;
                dst[n * 256 + k] = f2bf(w2[k * 64 + n]);
            }
        }
    }
}

// LayerNorm over d=64, transpose-gather into sequence-major bf16 y, pre-swizzled by (t&7)
__global__ __launch_bounds__(256) void ln_kernel(const float* __restrict__ x,
                                                 unsigned short* __restrict__ yb,
                                                 const float* __restrict__ gamma,
                                                 const float* __restrict__ beta,
                                                 int rmul, int tmul) {
    const int rowid = blockIdx.x * 4 + (threadIdx.x >> 6);
    const int lane  = threadIdx.x & 63;
    const int seq = rowid >> 7;
    const int t   = rowid & 127;
    const int b = seq >> 7;
    const int r = seq & 127;
    const size_t idx = (size_t)b * 1048576 + (size_t)r * rmul + (size_t)t * tmul + lane;
    float v = x[idx];
    float s1 = v;
#pragma unroll
    for (int m = 32; m >= 1; m >>= 1) s1 += __shfl_xor(s1, m);
    const float mu = s1 * (1.0f / 64.0f);
    const float dv = v - mu;
    float s2 = dv * dv;
#pragma unroll
    for (int m = 32; m >= 1; m >>= 1) s2 += __shfl_xor(s2, m);
    const float rstd = rsqrtf(s2 * (1.0f / 64.0f) + 1e-5f);
    const float nv = dv * rstd * gamma[lane] + beta[lane];
    const int c = lane >> 3, j = lane & 7;
    yb[(size_t)rowid * 64 + ((c ^ (t & 7)) << 3) + j] = f2bf(nv);
}

// spec[seq][l][e] = sum_{t<=l} sum_d y[t,d] * Gc[l-t,d,e]  via MFMA.
// 512 threads = 8 waves. 2 seqs/block. Wave w: grp=w>>2 (parity of s it computes),
// a=w&3 -> (sl=a>>1, wodd=a&1): seq sl, m-tiles {0,2,5,7}/{1,3,4,6}.
// Group 0 computes h=0 (even s) of each G-pair; group 1 computes h=1 (odd s).
// Quad-buffered pairs, stage(sp+3) after barrier (WAR-safe), counted vmcnt (T3/T4).
// Epilogue: group-1 f32 partials -> LDS (dead G bufs), group-0 adds + stores.
// LDS (ush): ys0 [0,9216) ys1 [9216,18432) Gbuf[p] 18432+p*8192 -> 100 KB
__global__ __launch_bounds__(512) void spec_kernel(const unsigned short* __restrict__ yb,
                                                   const unsigned short* __restrict__ Gct,
                                                   unsigned short* __restrict__ specb) {
    __shared__ unsigned short lds[51200];  // 100 KB
    const int tid = threadIdx.x;
    const int w = tid >> 6, lane = tid & 63;
    const int grp = w >> 2, a = w & 3;
    const int sl = a >> 1, wodd = a & 1;
    const int seq = blockIdx.x * 2 + sl;
    const int m = lane & 15, g = lane >> 4;
    const int ysb = sl * 9216;

    // zero prefix rows 0..15 of both ys regions (512 thr x 8 B = 4 KB)
    {
        uint2 z; z.x = 0u; z.y = 0u;
        *(uint2*)((char*)lds + (tid >> 8) * 18432 + (tid & 255) * 8) = z;
    }
    // stage ys rows 16..143: wave w stages 4 KB of seq (w>>2 pairs with both groups)
    {
        const char* ysrc = (const char*)yb + (size_t)(blockIdx.x * 2 + grp) * 16384 + a * 4096 + lane * 16;
        char* ydst = (char*)lds + grp * 18432 + 2048 + a * 4096;
#pragma unroll
        for (int i = 0; i < 4; ++i)
            __builtin_amdgcn_global_load_lds((const void*)(ysrc + i * 1024),
                                             (void*)(ydst + i * 1024), 16, 0, 0);
    }
    // prologue: stage G pairs 0,1,2 (each wave 2 x 1024 B per pair)
#pragma unroll
    for (int p = 0; p < 3; ++p) {
        const char* gsrc = (const char*)Gct + (size_t)p * 16384 + w * 2048 + lane * 16;
        char* gdst = (char*)lds + 36864 + p * 16384 + w * 2048;
#pragma unroll
        for (int i = 0; i < 2; ++i)
            __builtin_amdgcn_global_load_lds((const void*)(gsrc + i * 1024),
                                             (void*)(gdst + i * 1024), 16, 0, 0);
    }

    // B-read offsets within this wave's half-slice of a pair buffer
    int brel[4];
#pragma unroll
    for (int nt = 0; nt < 4; ++nt) {
        const int row = nt * 16 + m;
        brel[nt] = grp * 4096 + row * 64 + ((g ^ (row & 7)) << 3);
    }

    f32x4 acc[4][4];
#pragma unroll
    for (int j = 0; j < 4; ++j)
#pragma unroll
        for (int nt = 0; nt < 4; ++nt) {
            f32x4 z = {0.0f, 0.0f, 0.0f, 0.0f};
            acc[j][nt] = z;
        }

    for (int sp = 0; sp < 64; ++sp) {
        // wait for pair sp (keep pairs sp+1, sp+2 in flight = 4 loads/wave)
        if (sp == 0)       asm volatile("s_waitcnt vmcnt(4) lgkmcnt(0)" ::: "memory");
        else if (sp < 62)  asm volatile("s_waitcnt vmcnt(4)" ::: "memory");
        else if (sp == 62) asm volatile("s_waitcnt vmcnt(2)" ::: "memory");
        else               asm volatile("s_waitcnt vmcnt(0)" ::: "memory");
        __builtin_amdgcn_s_barrier();
        __builtin_amdgcn_sched_barrier(0);

        // stage pair sp+3 into buf (sp+3)&3 = buf of pair sp-1 (readers done before barrier)
        if (sp < 61) {
            const int p = sp + 3;
            const char* gsrc = (const char*)Gct + (size_t)p * 16384 + w * 2048 + lane * 16;
            char* gdst = (char*)lds + 36864 + (p & 3) * 16384 + w * 2048;
#pragma unroll
            for (int i = 0; i < 2; ++i)
                __builtin_amdgcn_global_load_lds((const void*)(gsrc + i * 1024),
                                                 (void*)(gdst + i * 1024), 16, 0, 0);
        }

        const int s = 2 * sp + grp;
        const int Gb = 18432 + (sp & 3) * 8192;
        bf16x8 b[4][2];
#pragma unroll
        for (int nt = 0; nt < 4; ++nt) {
            b[nt][0] = *(const bf16x8*)&lds[Gb + brel[nt]];
            b[nt][1] = *(const bf16x8*)&lds[Gb + (brel[nt] ^ 32)];
        }
#pragma unroll
        for (int j = 0; j < 4; ++j) {
            const int Ij = 2 * j + ((j & 2) ? (1 - wodd) : wodd);
            if (s <= Ij * 16 + 15) {
                const int row = 16 + Ij * 16 - s + m;
                const int c0 = (g ^ (row & 7)) << 3;
                const int abase = ysb + row * 64;
                bf16x8 a0 = *(const bf16x8*)&lds[abase + c0];
                bf16x8 a1 = *(const bf16x8*)&lds[abase + (c0 ^ 32)];
#pragma unroll
                for (int nt = 0; nt < 4; ++nt) {
                    acc[j][nt] = __builtin_amdgcn_mfma_f32_16x16x32_bf16(a0, b[nt][0], acc[j][nt], 0, 0, 0);
                    acc[j][nt] = __builtin_amdgcn_mfma_f32_16x16x32_bf16(a1, b[nt][1], acc[j][nt], 0, 0, 0);
                }
            }
        }
    }

    // ---- cross-group reduction (partials of wave 4+a match wave a) ----
    __syncthreads();  // all G-buf reads done; region reusable
    if (grp == 1) {
        char* pb = (char*)lds + 36864 + a * 16384 + lane * 16;
#pragma unroll
        for (int j = 0; j < 4; ++j)
#pragma unroll
            for (int nt = 0; nt < 4; ++nt)
                *(f32x4*)(pb + (j * 4 + nt) * 1024) = acc[j][nt];
    }
    __syncthreads();
    if (grp == 0) {
        const char* pb = (const char*)lds + 36864 + a * 16384 + lane * 16;
#pragma unroll
        for (int j = 0; j < 4; ++j)
#pragma unroll
            for (int nt = 0; nt < 4; ++nt) {
                f32x4 p = *(const f32x4*)(pb + (j * 4 + nt) * 1024);
                acc[j][nt] += p;
            }
        unsigned short* sp0 = specb + (size_t)seq * 8192;
#pragma unroll
        for (int j = 0; j < 4; ++j) {
            const int Ij = 2 * j + ((j & 2) ? (1 - wodd) : wodd);
#pragma unroll
            for (int nt = 0; nt < 4; ++nt)
#pragma unroll
                for (int r = 0; r < 4; ++r) {
                    const int row = Ij * 16 + 4 * g + r;
                    const int col = nt * 16 + m;
                    const int c = col >> 3;
                    sp0[row * 64 + ((c ^ (row & 7)) << 3) + (col & 7)] = f2bf(acc[j][nt][r]);
                }
        }
    }
}

// MLP via MFMA: out = xin + gelu(X@W1 + b1)@W2 + b2. One block per sequence.
// LDS (ush): X [0,8192), H [8192,40960) -> 80 KB. Weights from L2 into regs.
#define MX 0
#define MH 8192
__global__ __launch_bounds__(256) void mlp_kernel(const unsigned short* __restrict__ specb,
                                                  const unsigned short* __restrict__ w1t,
                                                  const unsigned short* __restrict__ w2t,
                                                  const float* __restrict__ b1,
                                                  const float* __restrict__ b2,
                                                  const float* __restrict__ xin,
                                                  float* __restrict__ xout,
                                                  int rmul, int tmul) {
    __shared__ unsigned short mld[40960];
    const int seq = blockIdx.x, tid = threadIdx.x;
    const int q = tid >> 6, lane = tid & 63;
    const int m = lane & 15, g = lane >> 4;

    {
        const char* xsrc = (const char*)specb + (size_t)seq * 16384 + q * 1024 + lane * 16;
#pragma unroll
        for (int i = 0; i < 4; ++i)
            __builtin_amdgcn_global_load_lds((const void*)(xsrc + i * 4096),
                                             (void*)&mld[MX + i * 2048 + q * 512], 16, 0, 0);
    }
    bf16x8 bw1[4][2];
#pragma unroll
    for (int nt = 0; nt < 4; ++nt) {
        const int row = q * 64 + nt * 16 + m;
#pragma unroll
        for (int j = 0; j < 2; ++j)
            bw1[nt][j] = *(const bf16x8*)&w1t[row * 64 + (4 * j + g) * 8];
    }
    float b1v[4];
#pragma unroll
    for (int nt = 0; nt < 4; ++nt) b1v[nt] = b1[q * 64 + nt * 16 + m];
    __syncthreads();  // X staged

    f32x4 acc1[8][4];
#pragma unroll
    for (int mt = 0; mt < 8; ++mt)
#pragma unroll
        for (int nt = 0; nt < 4; ++nt) {
            f32x4 z = {b1v[nt], b1v[nt], b1v[nt], b1v[nt]};
            acc1[mt][nt] = z;
        }
#pragma unroll
    for (int mt = 0; mt < 8; ++mt) {
        const int row = mt * 16 + m;
        const int c0 = (g ^ (row & 7)) << 3;
        bf16x8 a0 = *(const bf16x8*)&mld[MX + row * 64 + c0];
        bf16x8 a1 = *(const bf16x8*)&mld[MX + row * 64 + (c0 ^ 32)];
#pragma unroll
        for (int nt = 0; nt < 4; ++nt) {
            acc1[mt][nt] = __builtin_amdgcn_mfma_f32_16x16x32_bf16(a0, bw1[nt][0], acc1[mt][nt], 0, 0, 0);
            acc1[mt][nt] = __builtin_amdgcn_mfma_f32_16x16x32_bf16(a1, bw1[nt][1], acc1[mt][nt], 0, 0, 0);
        }
    }

#pragma unroll
    for (int mt = 0; mt < 8; ++mt)
#pragma unroll
        for (int nt = 0; nt < 4; ++nt) {
            const int col = q * 64 + nt * 16 + m;
            const int c = col >> 3, jj = col & 7;
#pragma unroll
            for (int r = 0; r < 4; ++r) {
                const int row = mt * 16 + 4 * g + r;
                mld[MH + row * 256 + ((c ^ (row & 7)) << 3) + jj] = f2bf(gelu_fast(acc1[mt][nt][r]));
            }
        }
    __syncthreads();  // H complete

    float b2v[4];
#pragma unroll
    for (int nt = 0; nt < 4; ++nt) b2v[nt] = b2[nt * 16 + m];
    f32x4 acc2[2][4];
#pragma unroll
    for (int mt = 0; mt < 2; ++mt)
#pragma unroll
        for (int nt = 0; nt < 4; ++nt) {
            f32x4 z = {b2v[nt], b2v[nt], b2v[nt], b2v[nt]};
            acc2[mt][nt] = z;
        }
#pragma unroll
    for (int j = 0; j < 8; ++j) {
        bf16x8 aa[2];
#pragma unroll
        for (int mt = 0; mt < 2; ++mt) {
            const int row = (q + 4 * mt) * 16 + m;
            aa[mt] = *(const bf16x8*)&mld[MH + row * 256 + (((4 * j + g) ^ (row & 7)) << 3)];
        }
#pragma unroll
        for (int nt = 0; nt < 4; ++nt) {
            const int row = nt * 16 + m;
            bf16x8 bfr = *(const bf16x8*)&w2t[row * 256 + (4 * j + g) * 8];
            acc2[0][nt] = __builtin_amdgcn_mfma_f32_16x16x32_bf16(aa[0], bfr, acc2[0][nt], 0, 0, 0);
            acc2[1][nt] = __builtin_amdgcn_mfma_f32_16x16x32_bf16(aa[1], bfr, acc2[1][nt], 0, 0, 0);
        }
    }

    const int b = seq >> 7, rr = seq & 127;
    const size_t base = (size_t)b * 1048576 + (size_t)rr * (size_t)rmul;
#pragma unroll
    for (int mt = 0; mt < 2; ++mt)
#pragma unroll
        for (int nt = 0; nt < 4; ++nt)
#pragma unroll
            for (int r = 0; r < 4; ++r) {
                const int row = (q + 4 * mt) * 16 + 4 * g + r;
                const int col = nt * 16 + m;
                const size_t xi = base + (size_t)row * tmul + col;
                xout[xi] = xin[xi] + acc2[mt][nt][r];
            }
}

extern "C" void kernel_launch(void* const* d_in, const int* in_sizes, int n_in,
                              void* d_out, int out_size, void* d_ws, size_t ws_size,
                              hipStream_t stream) {
    const float* v         = (const float*)d_in[0];
    const float* gamma_row = (const float*)d_in[1];
    const float* beta_row  = (const float*)d_in[2];
    const float* gamma_col = (const float*)d_in[3];
    const float* beta_col  = (const float*)d_in[4];
    const float* mp_row    = (const float*)d_in[5];
    const float* mm_row    = (const float*)d_in[6];
    const float* mp_col    = (const float*)d_in[7];
    const float* mm_col    = (const float*)d_in[8];
    const float* w1_row    = (const float*)d_in[9];
    const float* b1_row    = (const float*)d_in[10];
    const float* w2_row    = (const float*)d_in[11];
    const float* b2_row    = (const float*)d_in[12];
    const float* w1_col    = (const float*)d_in[13];
    const float* b1_col    = (const float*)d_in[14];
    const float* w2_col    = (const float*)d_in[15];
    const float* b2_col    = (const float*)d_in[16];
    const float* phi_row   = (const float*)d_in[17];
    const float* phi_col   = (const float*)d_in[18];
    float* out = (float*)d_out;
    char* ws   = (char*)d_ws;

    unsigned short* yb   = (unsigned short*)ws;                      // 8 MB
    unsigned short* spcb = (unsigned short*)(ws + (8u << 20));       // 8 MB
    unsigned short* GcR  = (unsigned short*)(ws + (16u << 20));      // 1 MB
    unsigned short* GcC  = (unsigned short*)(ws + (17u << 20));      // 1 MB
    unsigned short* w1tR = (unsigned short*)(ws + (18u << 20));
    unsigned short* w2tR = (unsigned short*)(ws + (18u << 20) + 32768);
    unsigned short* w1tC = (unsigned short*)(ws + (18u << 20) + 65536);
    unsigned short* w2tC = (unsigned short*)(ws + (18u << 20) + 98304);

    init_kernel<<<260, 256, 0, stream>>>(phi_row, mp_row, mm_row, GcR,
                                         phi_col, mp_col, mm_col, GcC,
                                         w1_row, w1_col, w2_row, w2_col,
                                         w1tR, w1tC, w2tR, w2tC);

    // row pass: seq=(b,h), t=w (stride 64)
    ln_kernel<<<16384, 256, 0, stream>>>(v, yb, gamma_row, beta_row, 8192, 64);
    spec_kernel<<<256, 512, 0, stream>>>(yb, GcR, spcb);
    mlp_kernel<<<512, 256, 0, stream>>>(spcb, w1tR, w2tR, b1_row, b2_row, v, out, 8192, 64);

    // col pass: seq=(b,w), t=h (stride 128*64)
    ln_kernel<<<16384, 256, 0, stream>>>(out, yb, gamma_col, beta_col, 64, 8192);
    spec_kernel<<<256, 512, 0, stream>>>(yb, GcC, spcb);
    mlp_kernel<<<512, 256, 0, stream>>>(spcb, w1tC, w2tC, b1_col, b2_col, out, out, 64, 8192);
}

// Round 7
// 163.282 us; speedup vs baseline: 21.6956x; 1.2060x over previous
//
#include <hip/hip_runtime.h>

#define DD   64
#define HIDN 256
#define LLEN 128

typedef __attribute__((ext_vector_type(8))) short bf16x8;
typedef __attribute__((ext_vector_type(4))) float f32x4;

__device__ __forceinline__ float gelu_fast(float x) {
    const float u = 0.7978845608028654f * x * (1.0f + 0.044715f * x * x);
    return x * __builtin_amdgcn_rcpf(1.0f + __expf(-2.0f * u));
}

__device__ __forceinline__ unsigned short f2bf(float x) {
    union { float f; unsigned int u; } v; v.f = x;
    unsigned int r = v.u + 0x7FFF + ((v.u >> 16) & 1);
    return (unsigned short)(r >> 16);
}

// blocks 0..31: Gct (coalesced reads, LDS transpose, swizzled 8B stores)
//   side = bid>>4, chunk = bid&15 covers elements i = chunk*256 + t, i=(d*64+e)
// blocks 32..35: weight transposes
__global__ __launch_bounds__(256) void init_kernel(const float* __restrict__ phi_r, const float* __restrict__ mp_r,
                                                   const float* __restrict__ mm_r, unsigned short* __restrict__ GcR,
                                                   const float* __restrict__ phi_c, const float* __restrict__ mp_c,
                                                   const float* __restrict__ mm_c, unsigned short* __restrict__ GcC,
                                                   const float* __restrict__ w1r, const float* __restrict__ w1c,
                                                   const float* __restrict__ w2r, const float* __restrict__ w2c,
                                                   unsigned short* __restrict__ w1tr, unsigned short* __restrict__ w1tc,
                                                   unsigned short* __restrict__ w2tr, unsigned short* __restrict__ w2tc) {
    const int bid = blockIdx.x, tid = threadIdx.x;
    if (bid < 32) {
        __shared__ float phis[2048];
        __shared__ unsigned short tile[4096];  // 16 s x 256 (e-major, d-minor)
        const int side = bid >> 4, chunk = bid & 15;
        const float* phi = side ? phi_c : phi_r;
        const float* mp  = side ? mp_c  : mp_r;
        const float* mm  = side ? mm_c  : mm_r;
        unsigned short* Gct = side ? GcC : GcR;
        const int i = chunk * 256 + tid;
        float pe[16], po[16];
#pragma unroll
        for (int k = 0; k < 16; ++k) {
            const float a = mp[k * 4096 + i];
            const float b = mm[k * 4096 + i];
            pe[k] = a + b; po[k] = a - b;
        }
        for (int j = tid; j < 2048; j += 256) phis[j] = phi[j];
        __syncthreads();
        const int e = tid & 63, dl = tid >> 6;
        const int d0 = chunk * 4;
        const int cc = d0 >> 3, jlo = d0 & 7;
        for (int s0 = 0; s0 < 128; s0 += 16) {
#pragma unroll
            for (int sb = 0; sb < 16; ++sb) {
                const int s = s0 + sb;
                const float* pk = &phis[s * 16];
                float acc = 0.0f;
                if (s & 1) {
#pragma unroll
                    for (int k = 0; k < 16; ++k) acc += pk[k] * po[k];
                } else {
#pragma unroll
                    for (int k = 0; k < 16; ++k) acc += pk[k] * pe[k];
                }
                tile[sb * 256 + e * 4 + dl] = f2bf(acc);
            }
            __syncthreads();
#pragma unroll
            for (int it = 0; it < 4; ++it) {
                const int p = it * 256 + tid;
                const int sb = p >> 6, ee = p & 63;
                uint2 v = *(const uint2*)&tile[sb * 256 + ee * 4];
                *(uint2*)&Gct[(size_t)(s0 + sb) * 4096 + ee * 64 + ((cc ^ (ee & 7)) << 3) + jlo] = v;
            }
            __syncthreads();
        }
    } else {
        const int b = bid - 32;
        if (b < 2) {
            const float* w1 = b ? w1c : w1r;
            unsigned short* dst = b ? w1tc : w1tr;
            const int n = tid;
            for (int k = 0; k < 64; ++k) dst[n * 64 + k] = f2bf(w1[k * 256 + n]);
        } else {
            const float* w2 = (b == 3) ? w2c : w2r;
            unsigned short* dst = (b == 3) ? w2tc : w2tr;
            const int n = tid & 63, kq = tid >> 6;
            for (int kk = 0; kk < 64; ++kk) {
                const int k = kq * 64 + kk;
                dst[n * 256 + k] = f2bf(w2[k * 64 + n]);
            }
        }
    }
}

// LayerNorm over d=64, transpose-gather into sequence-major bf16 y, pre-swizzled by (t&7)
__global__ __launch_bounds__(256) void ln_kernel(const float* __restrict__ x,
                                                 unsigned short* __restrict__ yb,
                                                 const float* __restrict__ gamma,
                                                 const float* __restrict__ beta,
                                                 int rmul, int tmul) {
    const int rowid = blockIdx.x * 4 + (threadIdx.x >> 6);
    const int lane  = threadIdx.x & 63;
    const int seq = rowid >> 7;
    const int t   = rowid & 127;
    const int b = seq >> 7;
    const int r = seq & 127;
    const size_t idx = (size_t)b * 1048576 + (size_t)r * rmul + (size_t)t * tmul + lane;
    float v = x[idx];
    float s1 = v;
#pragma unroll
    for (int m = 32; m >= 1; m >>= 1) s1 += __shfl_xor(s1, m);
    const float mu = s1 * (1.0f / 64.0f);
    const float dv = v - mu;
    float s2 = dv * dv;
#pragma unroll
    for (int m = 32; m >= 1; m >>= 1) s2 += __shfl_xor(s2, m);
    const float rstd = rsqrtf(s2 * (1.0f / 64.0f) + 1e-5f);
    const float nv = dv * rstd * gamma[lane] + beta[lane];
    const int c = lane >> 3, j = lane & 7;
    yb[(size_t)rowid * 64 + ((c ^ (t & 7)) << 3) + j] = f2bf(nv);
}

// spec[seq][l][e] = sum_{t<=l} sum_d y[t,d] * Gc[l-t,d,e]  via MFMA.
// 512 threads = 8 waves, 2 seqs/block. Wave w: slice-residue ss=w>>1, seq sl=w&1.
// Per round r (4 slices = 32 KB, triple-buffered): wave computes slice s=4r+ss for
// seq sl across ALL 8 m-tiles (acc[8][4]) -> B-reads amortize 2x vs R6.
// stage(r+2) after barrier (WAR-safe), counted vmcnt(4), 32 barriers.
// Epilogue: 2-phase LDS tree reduction over ss in {0..3}, waves ss=0 store.
// LDS (ush): ys0 [0,9216) ys1 [9216,18432) Gbuf[b] 18432+b*16384, b=0..2 -> 132 KB
__global__ __launch_bounds__(512, 2) void spec_kernel(const unsigned short* __restrict__ yb,
                                                      const unsigned short* __restrict__ Gct,
                                                      unsigned short* __restrict__ specb) {
    __shared__ unsigned short lds[67584];  // 132 KB
    const int tid = threadIdx.x;
    const int w = tid >> 6, lane = tid & 63;
    const int ss = w >> 1, sl = w & 1;
    const int seq = blockIdx.x * 2 + sl;
    const int m = lane & 15, g = lane >> 4;
    const int ysb = sl * 9216;

    // zero prefix rows 0..15 of both ys regions (512 thr x 8 B = 4 KB)
    {
        uint2 z; z.x = 0u; z.y = 0u;
        *(uint2*)((char*)lds + (tid >> 8) * 18432 + (tid & 255) * 8) = z;
    }
    // stage ys rows 16..143: wave w stages 4 KB chunk (w>>1) of seq (w&1)
    {
        const char* ysrc = (const char*)yb + (size_t)(blockIdx.x * 2 + sl) * 16384 + ss * 4096 + lane * 16;
        char* ydst = (char*)lds + sl * 18432 + 2048 + ss * 4096;
#pragma unroll
        for (int i = 0; i < 4; ++i)
            __builtin_amdgcn_global_load_lds((const void*)(ysrc + i * 1024),
                                             (void*)(ydst + i * 1024), 16, 0, 0);
    }
    // prologue: stage rounds 0,1 (each wave 4 KB per round)
#pragma unroll
    for (int p = 0; p < 2; ++p) {
        const char* gsrc = (const char*)Gct + (size_t)p * 32768 + w * 4096 + lane * 16;
        char* gdst = (char*)lds + 36864 + p * 32768 + w * 4096;
#pragma unroll
        for (int i = 0; i < 4; ++i)
            __builtin_amdgcn_global_load_lds((const void*)(gsrc + i * 1024),
                                             (void*)(gdst + i * 1024), 16, 0, 0);
    }

    int brel[4];
#pragma unroll
    for (int nt = 0; nt < 4; ++nt) {
        const int row = nt * 16 + m;
        brel[nt] = row * 64 + ((g ^ (row & 7)) << 3);
    }

    f32x4 acc[8][4];
#pragma unroll
    for (int j = 0; j < 8; ++j)
#pragma unroll
        for (int nt = 0; nt < 4; ++nt) {
            f32x4 z = {0.0f, 0.0f, 0.0f, 0.0f};
            acc[j][nt] = z;
        }

    int bufc = 0, bufs = 2;
    for (int r = 0; r < 32; ++r) {
        if (r == 0)      asm volatile("s_waitcnt vmcnt(4) lgkmcnt(0)" ::: "memory");
        else if (r < 31) asm volatile("s_waitcnt vmcnt(4)" ::: "memory");
        else             asm volatile("s_waitcnt vmcnt(0)" ::: "memory");
        __builtin_amdgcn_s_barrier();
        __builtin_amdgcn_sched_barrier(0);

        // stage round r+2 into buf of round r-1 (its readers finished before barrier r)
        if (r <= 29) {
            const char* gsrc = (const char*)Gct + (size_t)(r + 2) * 32768 + w * 4096 + lane * 16;
            char* gdst = (char*)lds + 36864 + bufs * 32768 + w * 4096;
#pragma unroll
            for (int i = 0; i < 4; ++i)
                __builtin_amdgcn_global_load_lds((const void*)(gsrc + i * 1024),
                                                 (void*)(gdst + i * 1024), 16, 0, 0);
        }

        const int s = 4 * r + ss;
        const int jmin = __builtin_amdgcn_readfirstlane(s >> 4);
        const int Gb = 18432 + bufc * 16384 + ss * 4096;
        bf16x8 b[4][2];
#pragma unroll
        for (int nt = 0; nt < 4; ++nt) {
            b[nt][0] = *(const bf16x8*)&lds[Gb + brel[nt]];
            b[nt][1] = *(const bf16x8*)&lds[Gb + (brel[nt] ^ 32)];
        }
#pragma unroll
        for (int j = 0; j < 8; ++j) {
            if (j >= jmin) {
                const int row = 16 + 16 * j - s + m;
                const int c0 = (g ^ (row & 7)) << 3;
                const int abase = ysb + row * 64;
                bf16x8 a0 = *(const bf16x8*)&lds[abase + c0];
                bf16x8 a1 = *(const bf16x8*)&lds[abase + (c0 ^ 32)];
#pragma unroll
                for (int nt = 0; nt < 4; ++nt) {
                    acc[j][nt] = __builtin_amdgcn_mfma_f32_16x16x32_bf16(a0, b[nt][0], acc[j][nt], 0, 0, 0);
                    acc[j][nt] = __builtin_amdgcn_mfma_f32_16x16x32_bf16(a1, b[nt][1], acc[j][nt], 0, 0, 0);
                }
            }
        }
        bufc = (bufc == 2) ? 0 : bufc + 1;
        bufs = (bufs == 2) ? 0 : bufs + 1;
    }

    // ---- 2-phase cross-wave reduction over ss ----
    __syncthreads();  // all LDS now dead
    if (w >= 4) {     // ss in {2,3} dump
        char* pb = (char*)lds + (w - 4) * 32768 + lane * 16;
#pragma unroll
        for (int j = 0; j < 8; ++j)
#pragma unroll
            for (int nt = 0; nt < 4; ++nt)
                *(f32x4*)(pb + (j * 4 + nt) * 1024) = acc[j][nt];
    }
    __syncthreads();
    if (w < 4) {      // ss in {0,1} add partner ss+2
        const char* pb = (const char*)lds + w * 32768 + lane * 16;
#pragma unroll
        for (int j = 0; j < 8; ++j)
#pragma unroll
            for (int nt = 0; nt < 4; ++nt)
                acc[j][nt] += *(const f32x4*)(pb + (j * 4 + nt) * 1024);
    }
    __syncthreads();
    if (w == 2 || w == 3) {  // ss=1 (combined 1+3) dump
        char* pb = (char*)lds + (w - 2) * 32768 + lane * 16;
#pragma unroll
        for (int j = 0; j < 8; ++j)
#pragma unroll
            for (int nt = 0; nt < 4; ++nt)
                *(f32x4*)(pb + (j * 4 + nt) * 1024) = acc[j][nt];
    }
    __syncthreads();
    if (w < 2) {             // ss=0 (combined 0+2) add -> full sum, store
        const char* pb = (const char*)lds + w * 32768 + lane * 16;
#pragma unroll
        for (int j = 0; j < 8; ++j)
#pragma unroll
            for (int nt = 0; nt < 4; ++nt)
                acc[j][nt] += *(const f32x4*)(pb + (j * 4 + nt) * 1024);
        unsigned short* sp0 = specb + (size_t)seq * 8192;
#pragma unroll
        for (int j = 0; j < 8; ++j)
#pragma unroll
            for (int nt = 0; nt < 4; ++nt)
#pragma unroll
                for (int rr = 0; rr < 4; ++rr) {
                    const int row = j * 16 + 4 * g + rr;
                    const int col = nt * 16 + m;
                    const int c = col >> 3;
                    sp0[row * 64 + ((c ^ (row & 7)) << 3) + (col & 7)] = f2bf(acc[j][nt][rr]);
                }
    }
}

// MLP via MFMA: out = xin + gelu(X@W1 + b1)@W2 + b2. One block per sequence.
// LDS (ush): X [0,8192), H [8192,40960) -> 80 KB. Weights from L2 into regs.
#define MX 0
#define MH 8192
__global__ __launch_bounds__(256) void mlp_kernel(const unsigned short* __restrict__ specb,
                                                  const unsigned short* __restrict__ w1t,
                                                  const unsigned short* __restrict__ w2t,
                                                  const float* __restrict__ b1,
                                                  const float* __restrict__ b2,
                                                  const float* __restrict__ xin,
                                                  float* __restrict__ xout,
                                                  int rmul, int tmul) {
    __shared__ unsigned short mld[40960];
    const int seq = blockIdx.x, tid = threadIdx.x;
    const int q = tid >> 6, lane = tid & 63;
    const int m = lane & 15, g = lane >> 4;

    {
        const char* xsrc = (const char*)specb + (size_t)seq * 16384 + q * 1024 + lane * 16;
#pragma unroll
        for (int i = 0; i < 4; ++i)
            __builtin_amdgcn_global_load_lds((const void*)(xsrc + i * 4096),
                                             (void*)&mld[MX + i * 2048 + q * 512], 16, 0, 0);
    }
    bf16x8 bw1[4][2];
#pragma unroll
    for (int nt = 0; nt < 4; ++nt) {
        const int row = q * 64 + nt * 16 + m;
#pragma unroll
        for (int j = 0; j < 2; ++j)
            bw1[nt][j] = *(const bf16x8*)&w1t[row * 64 + (4 * j + g) * 8];
    }
    float b1v[4];
#pragma unroll
    for (int nt = 0; nt < 4; ++nt) b1v[nt] = b1[q * 64 + nt * 16 + m];
    __syncthreads();  // X staged

    f32x4 acc1[8][4];
#pragma unroll
    for (int mt = 0; mt < 8; ++mt)
#pragma unroll
        for (int nt = 0; nt < 4; ++nt) {
            f32x4 z = {b1v[nt], b1v[nt], b1v[nt], b1v[nt]};
            acc1[mt][nt] = z;
        }
#pragma unroll
    for (int mt = 0; mt < 8; ++mt) {
        const int row = mt * 16 + m;
        const int c0 = (g ^ (row & 7)) << 3;
        bf16x8 a0 = *(const bf16x8*)&mld[MX + row * 64 + c0];
        bf16x8 a1 = *(const bf16x8*)&mld[MX + row * 64 + (c0 ^ 32)];
#pragma unroll
        for (int nt = 0; nt < 4; ++nt) {
            acc1[mt][nt] = __builtin_amdgcn_mfma_f32_16x16x32_bf16(a0, bw1[nt][0], acc1[mt][nt], 0, 0, 0);
            acc1[mt][nt] = __builtin_amdgcn_mfma_f32_16x16x32_bf16(a1, bw1[nt][1], acc1[mt][nt], 0, 0, 0);
        }
    }

#pragma unroll
    for (int mt = 0; mt < 8; ++mt)
#pragma unroll
        for (int nt = 0; nt < 4; ++nt) {
            const int col = q * 64 + nt * 16 + m;
            const int c = col >> 3, jj = col & 7;
#pragma unroll
            for (int r = 0; r < 4; ++r) {
                const int row = mt * 16 + 4 * g + r;
                mld[MH + row * 256 + ((c ^ (row & 7)) << 3) + jj] = f2bf(gelu_fast(acc1[mt][nt][r]));
            }
        }
    __syncthreads();  // H complete

    float b2v[4];
#pragma unroll
    for (int nt = 0; nt < 4; ++nt) b2v[nt] = b2[nt * 16 + m];
    f32x4 acc2[2][4];
#pragma unroll
    for (int mt = 0; mt < 2; ++mt)
#pragma unroll
        for (int nt = 0; nt < 4; ++nt) {
            f32x4 z = {b2v[nt], b2v[nt], b2v[nt], b2v[nt]};
            acc2[mt][nt] = z;
        }
#pragma unroll
    for (int j = 0; j < 8; ++j) {
        bf16x8 aa[2];
#pragma unroll
        for (int mt = 0; mt < 2; ++mt) {
            const int row = (q + 4 * mt) * 16 + m;
            aa[mt] = *(const bf16x8*)&mld[MH + row * 256 + (((4 * j + g) ^ (row & 7)) << 3)];
        }
#pragma unroll
        for (int nt = 0; nt < 4; ++nt) {
            const int row = nt * 16 + m;
            bf16x8 bfr = *(const bf16x8*)&w2t[row * 256 + (4 * j + g) * 8];
            acc2[0][nt] = __builtin_amdgcn_mfma_f32_16x16x32_bf16(aa[0], bfr, acc2[0][nt], 0, 0, 0);
            acc2[1][nt] = __builtin_amdgcn_mfma_f32_16x16x32_bf16(aa[1], bfr, acc2[1][nt], 0, 0, 0);
        }
    }

    const int b = seq >> 7, rr = seq & 127;
    const size_t base = (size_t)b * 1048576 + (size_t)rr * (size_t)rmul;
#pragma unroll
    for (int mt = 0; mt < 2; ++mt)
#pragma unroll
        for (int nt = 0; nt < 4; ++nt)
#pragma unroll
            for (int r = 0; r < 4; ++r) {
                const int row = (q + 4 * mt) * 16 + 4 * g + r;
                const int col = nt * 16 + m;
                const size_t xi = base + (size_t)row * tmul + col;
                xout[xi] = xin[xi] + acc2[mt][nt][r];
            }
}

extern "C" void kernel_launch(void* const* d_in, const int* in_sizes, int n_in,
                              void* d_out, int out_size, void* d_ws, size_t ws_size,
                              hipStream_t stream) {
    const float* v         = (const float*)d_in[0];
    const float* gamma_row = (const float*)d_in[1];
    const float* beta_row  = (const float*)d_in[2];
    const float* gamma_col = (const float*)d_in[3];
    const float* beta_col  = (const float*)d_in[4];
    const float* mp_row    = (const float*)d_in[5];
    const float* mm_row    = (const float*)d_in[6];
    const float* mp_col    = (const float*)d_in[7];
    const float* mm_col    = (const float*)d_in[8];
    const float* w1_row    = (const float*)d_in[9];
    const float* b1_row    = (const float*)d_in[10];
    const float* w2_row    = (const float*)d_in[11];
    const float* b2_row    = (const float*)d_in[12];
    const float* w1_col    = (const float*)d_in[13];
    const float* b1_col    = (const float*)d_in[14];
    const float* w2_col    = (const float*)d_in[15];
    const float* b2_col    = (const float*)d_in[16];
    const float* phi_row   = (const float*)d_in[17];
    const float* phi_col   = (const float*)d_in[18];
    float* out = (float*)d_out;
    char* ws   = (char*)d_ws;

    unsigned short* yb   = (unsigned short*)ws;                      // 8 MB
    unsigned short* spcb = (unsigned short*)(ws + (8u << 20));       // 8 MB
    unsigned short* GcR  = (unsigned short*)(ws + (16u << 20));      // 1 MB
    unsigned short* GcC  = (unsigned short*)(ws + (17u << 20));      // 1 MB
    unsigned short* w1tR = (unsigned short*)(ws + (18u << 20));
    unsigned short* w2tR = (unsigned short*)(ws + (18u << 20) + 32768);
    unsigned short* w1tC = (unsigned short*)(ws + (18u << 20) + 65536);
    unsigned short* w2tC = (unsigned short*)(ws + (18u << 20) + 98304);

    init_kernel<<<36, 256, 0, stream>>>(phi_row, mp_row, mm_row, GcR,
                                        phi_col, mp_col, mm_col, GcC,
                                        w1_row, w1_col, w2_row, w2_col,
                                        w1tR, w1tC, w2tR, w2tC);

    // row pass: seq=(b,h), t=w (stride 64)
    ln_kernel<<<16384, 256, 0, stream>>>(v, yb, gamma_row, beta_row, 8192, 64);
    spec_kernel<<<256, 512, 0, stream>>>(yb, GcR, spcb);
    mlp_kernel<<<512, 256, 0, stream>>>(spcb, w1tR, w2tR, b1_row, b2_row, v, out, 8192, 64);

    // col pass: seq=(b,w), t=h (stride 128*64)
    ln_kernel<<<16384, 256, 0, stream>>>(out, yb, gamma_col, beta_col, 64, 8192);
    spec_kernel<<<256, 512, 0, stream>>>(yb, GcC, spcb);
    mlp_kernel<<<512, 256, 0, stream>>>(spcb, w1tC, w2tC, b1_col, b2_col, out, out, 64, 8192);
}

// Round 8
// 157.217 us; speedup vs baseline: 22.5325x; 1.0386x over previous
//
#include <hip/hip_runtime.h>

#define DD   64
#define HIDN 256
#define LLEN 128

typedef __attribute__((ext_vector_type(8))) short bf16x8;
typedef __attribute__((ext_vector_type(4))) float f32x4;

__device__ __forceinline__ float gelu_fast(float x) {
    const float u = 0.7978845608028654f * x * (1.0f + 0.044715f * x * x);
    return x * __builtin_amdgcn_rcpf(1.0f + __expf(-2.0f * u));
}

__device__ __forceinline__ unsigned short f2bf(float x) {
    union { float f; unsigned int u; } v; v.f = x;
    unsigned int r = v.u + 0x7FFF + ((v.u >> 16) & 1);
    return (unsigned short)(r >> 16);
}

// blocks 0..31: Gf fragment-major: Gf[s][frag=nt*2+kk][lane=g*16+m][8] holds
//   Gc[s][e=nt*16+m][d=kk*32+g*8 .. +8) as bf16 -> spec's B-loads are coalesced dwordx4.
// blocks 32..35: weight transposes.
__global__ __launch_bounds__(256) void init_kernel(const float* __restrict__ phi_r, const float* __restrict__ mp_r,
                                                   const float* __restrict__ mm_r, unsigned short* __restrict__ GcR,
                                                   const float* __restrict__ phi_c, const float* __restrict__ mp_c,
                                                   const float* __restrict__ mm_c, unsigned short* __restrict__ GcC,
                                                   const float* __restrict__ w1r, const float* __restrict__ w1c,
                                                   const float* __restrict__ w2r, const float* __restrict__ w2c,
                                                   unsigned short* __restrict__ w1tr, unsigned short* __restrict__ w1tc,
                                                   unsigned short* __restrict__ w2tr, unsigned short* __restrict__ w2tc) {
    const int bid = blockIdx.x, tid = threadIdx.x;
    if (bid < 32) {
        __shared__ float phis[2048];
        __shared__ unsigned short tile[4096];  // 16 s x 256 (e-major, d-minor)
        const int side = bid >> 4, chunk = bid & 15;
        const float* phi = side ? phi_c : phi_r;
        const float* mp  = side ? mp_c  : mp_r;
        const float* mm  = side ? mm_c  : mm_r;
        unsigned short* Gct = side ? GcC : GcR;
        const int i = chunk * 256 + tid;
        float pe[16], po[16];
#pragma unroll
        for (int k = 0; k < 16; ++k) {
            const float a = mp[k * 4096 + i];
            const float b = mm[k * 4096 + i];
            pe[k] = a + b; po[k] = a - b;
        }
        for (int j = tid; j < 2048; j += 256) phis[j] = phi[j];
        __syncthreads();
        const int e = tid & 63, dl = tid >> 6;
        const int d0 = chunk * 4;                    // this block owns d in [d0, d0+4)
        const int kk = d0 >> 5, g3 = (d0 >> 3) & 3, jl0 = d0 & 7;
        for (int s0 = 0; s0 < 128; s0 += 16) {
#pragma unroll
            for (int sb = 0; sb < 16; ++sb) {
                const int s = s0 + sb;
                const float* pk = &phis[s * 16];
                float acc = 0.0f;
                if (s & 1) {
#pragma unroll
                    for (int k = 0; k < 16; ++k) acc += pk[k] * po[k];
                } else {
#pragma unroll
                    for (int k = 0; k < 16; ++k) acc += pk[k] * pe[k];
                }
                tile[sb * 256 + e * 4 + dl] = f2bf(acc);
            }
            __syncthreads();
#pragma unroll
            for (int it = 0; it < 4; ++it) {
                const int p = it * 256 + tid;
                const int sb = p >> 6, ee = p & 63;
                uint2 v = *(const uint2*)&tile[sb * 256 + ee * 4];
                *(uint2*)&Gct[(size_t)(s0 + sb) * 4096 + (((ee >> 4) << 1) + kk) * 512 +
                              (g3 * 16 + (ee & 15)) * 8 + jl0] = v;
            }
            __syncthreads();
        }
    } else {
        const int b = bid - 32;
        if (b < 2) {
            const float* w1 = b ? w1c : w1r;
            unsigned short* dst = b ? w1tc : w1tr;
            const int n = tid;
            for (int k = 0; k < 64; ++k) dst[n * 64 + k] = f2bf(w1[k * 256 + n]);
        } else {
            const float* w2 = (b == 3) ? w2c : w2r;
            unsigned short* dst = (b == 3) ? w2tc : w2tr;
            const int n = tid & 63, kq = tid >> 6;
            for (int kk2 = 0; kk2 < 64; ++kk2) {
                const int k = kq * 64 + kk2;
                dst[n * 256 + k] = f2bf(w2[k * 64 + n]);
            }
        }
    }
}

// LayerNorm over d=64, transpose-gather into sequence-major bf16 y, pre-swizzled by (t&7)
__global__ __launch_bounds__(256) void ln_kernel(const float* __restrict__ x,
                                                 unsigned short* __restrict__ yb,
                                                 const float* __restrict__ gamma,
                                                 const float* __restrict__ beta,
                                                 int rmul, int tmul) {
    const int rowid = blockIdx.x * 4 + (threadIdx.x >> 6);
    const int lane  = threadIdx.x & 63;
    const int seq = rowid >> 7;
    const int t   = rowid & 127;
    const int b = seq >> 7;
    const int r = seq & 127;
    const size_t idx = (size_t)b * 1048576 + (size_t)r * rmul + (size_t)t * tmul + lane;
    float v = x[idx];
    float s1 = v;
#pragma unroll
    for (int m = 32; m >= 1; m >>= 1) s1 += __shfl_xor(s1, m);
    const float mu = s1 * (1.0f / 64.0f);
    const float dv = v - mu;
    float s2 = dv * dv;
#pragma unroll
    for (int m = 32; m >= 1; m >>= 1) s2 += __shfl_xor(s2, m);
    const float rstd = rsqrtf(s2 * (1.0f / 64.0f) + 1e-5f);
    const float nv = dv * rstd * gamma[lane] + beta[lane];
    const int c = lane >> 3, j = lane & 7;
    yb[(size_t)rowid * 64 + ((c ^ (t & 7)) << 3) + j] = f2bf(nv);
}

// spec[seq][l][e] = sum_{t<=l} sum_d y[t,d] * Gc[l-t,d,e]  via MFMA.
// 1 seq/block, 256 threads = 4 waves, grid 512 (2 blocks/CU). Wave w = s-residue mod 4.
// NO main-loop barriers: B-fragments stream global(L2)->regs (frag-major Gf, coalesced),
// 2-deep static double buffer Ba/Bb; A from LDS ys (swizzled, read-only after one barrier).
// Epilogue: 2-phase scratch reduction; w0 stores j=0..3, w1 stores j=4..7.
// LDS bytes: ys [0,18432), scratch 3 x 16 KB at 18432 -> 66 KB total.
#define SPEC_BODY(RR, BC, BN)                                                        \
    {                                                                                \
        const int s_ = 4 * (RR) + w;                                                 \
        if ((RR) < 31) {                                                             \
            const unsigned short* gq = Gf + (size_t)(s_ + 4) * 4096 + lane * 8;      \
            _Pragma("unroll")                                                        \
            for (int f = 0; f < 8; ++f) BN[f] = *(const bf16x8*)(gq + f * 512);      \
        }                                                                            \
        const int jmin_ = __builtin_amdgcn_readfirstlane(s_ >> 4);                   \
        _Pragma("unroll")                                                            \
        for (int j = 0; j < 8; ++j) {                                                \
            if (j >= jmin_) {                                                        \
                const int row_ = 16 + 16 * j - s_ + m;                               \
                const int c0_ = (g ^ (row_ & 7)) << 3;                               \
                const int ab_ = row_ * 64;                                           \
                bf16x8 a0_ = *(const bf16x8*)&lds[ab_ + c0_];                        \
                bf16x8 a1_ = *(const bf16x8*)&lds[ab_ + (c0_ ^ 32)];                 \
                _Pragma("unroll")                                                    \
                for (int nt = 0; nt < 4; ++nt) {                                     \
                    acc[j][nt] = __builtin_amdgcn_mfma_f32_16x16x32_bf16(a0_, BC[2 * nt], acc[j][nt], 0, 0, 0);     \
                    acc[j][nt] = __builtin_amdgcn_mfma_f32_16x16x32_bf16(a1_, BC[2 * nt + 1], acc[j][nt], 0, 0, 0); \
                }                                                                    \
            }                                                                        \
        }                                                                            \
    }

__global__ __launch_bounds__(256, 2) void spec_kernel(const unsigned short* __restrict__ yb,
                                                      const unsigned short* __restrict__ Gf,
                                                      unsigned short* __restrict__ specb) {
    __shared__ unsigned short lds[33792];  // 66 KB
    const int tid = threadIdx.x;
    const int w = tid >> 6, lane = tid & 63;
    const int seq = blockIdx.x;
    const int m = lane & 15, g = lane >> 4;

    // zero prefix rows 0..15 (bytes [0,2048))
    {
        uint2 z; z.x = 0u; z.y = 0u;
        *(uint2*)((char*)lds + tid * 8) = z;
    }
    // stage ys rows 16..143 (16 KB) at bytes [2048,18432); yb pre-swizzled -> linear copy
    {
        const char* ysrc = (const char*)yb + (size_t)seq * 16384 + w * 1024 + lane * 16;
        char* ydst = (char*)lds + 2048 + w * 1024 + lane * 16;
#pragma unroll
        for (int i = 0; i < 4; ++i)
            __builtin_amdgcn_global_load_lds((const void*)(ysrc + i * 4096),
                                             (void*)(ydst + i * 4096), 16, 0, 0);
    }
    __syncthreads();

    f32x4 acc[8][4];
#pragma unroll
    for (int j = 0; j < 8; ++j)
#pragma unroll
        for (int nt = 0; nt < 4; ++nt) {
            f32x4 z = {0.0f, 0.0f, 0.0f, 0.0f};
            acc[j][nt] = z;
        }

    bf16x8 Ba[8], Bb[8];
    {
        const unsigned short* gq = Gf + (size_t)w * 4096 + lane * 8;  // s = w (round 0)
#pragma unroll
        for (int f = 0; f < 8; ++f) Ba[f] = *(const bf16x8*)(gq + f * 512);
    }
    for (int rp = 0; rp < 16; ++rp) {
        SPEC_BODY(2 * rp,     Ba, Bb);
        SPEC_BODY(2 * rp + 1, Bb, Ba);
    }

    // ---- epilogue reduction ----
    // phase 1: waves 1,2,3 dump j=0..3; w0 reduces
    if (w != 0) {
        char* pb = (char*)lds + 18432 + (w - 1) * 16384 + lane * 16;
#pragma unroll
        for (int j = 0; j < 4; ++j)
#pragma unroll
            for (int nt = 0; nt < 4; ++nt)
                *(f32x4*)(pb + (j * 4 + nt) * 1024) = acc[j][nt];
    }
    __syncthreads();
    if (w == 0) {
#pragma unroll
        for (int j = 0; j < 4; ++j)
#pragma unroll
            for (int nt = 0; nt < 4; ++nt)
#pragma unroll
                for (int sw = 0; sw < 3; ++sw)
                    acc[j][nt] += *(const f32x4*)((const char*)lds + 18432 + sw * 16384 +
                                                  (j * 4 + nt) * 1024 + lane * 16);
    }
    __syncthreads();  // w0 done reading scratch before phase-2 dumps
    // phase 2: waves 0,2,3 dump j=4..7; w1 reduces
    if (w != 1) {
        const int ri = (w == 0) ? 0 : (w - 1);
        char* pb = (char*)lds + 18432 + ri * 16384 + lane * 16;
#pragma unroll
        for (int j = 4; j < 8; ++j)
#pragma unroll
            for (int nt = 0; nt < 4; ++nt)
                *(f32x4*)(pb + ((j - 4) * 4 + nt) * 1024) = acc[j][nt];
    }
    unsigned short* sp0 = specb + (size_t)seq * 8192;
    if (w == 0) {  // store j=0..3 (global only, overlaps phase 2)
#pragma unroll
        for (int j = 0; j < 4; ++j)
#pragma unroll
            for (int nt = 0; nt < 4; ++nt)
#pragma unroll
                for (int rv = 0; rv < 4; ++rv) {
                    const int row = j * 16 + 4 * g + rv;
                    const int col = nt * 16 + m;
                    sp0[row * 64 + (((col >> 3) ^ (row & 7)) << 3) + (col & 7)] = f2bf(acc[j][nt][rv]);
                }
    }
    __syncthreads();
    if (w == 1) {
#pragma unroll
        for (int j = 4; j < 8; ++j)
#pragma unroll
            for (int nt = 0; nt < 4; ++nt)
#pragma unroll
                for (int sw = 0; sw < 3; ++sw)
                    acc[j][nt] += *(const f32x4*)((const char*)lds + 18432 + sw * 16384 +
                                                  ((j - 4) * 4 + nt) * 1024 + lane * 16);
#pragma unroll
        for (int j = 4; j < 8; ++j)
#pragma unroll
            for (int nt = 0; nt < 4; ++nt)
#pragma unroll
                for (int rv = 0; rv < 4; ++rv) {
                    const int row = j * 16 + 4 * g + rv;
                    const int col = nt * 16 + m;
                    sp0[row * 64 + (((col >> 3) ^ (row & 7)) << 3) + (col & 7)] = f2bf(acc[j][nt][rv]);
                }
    }
}

// MLP via MFMA: out = xin + gelu(X@W1 + b1)@W2 + b2. One block per sequence.
// LDS (ush): X [0,8192), H [8192,40960) -> 80 KB. Weights from L2 into regs.
#define MX 0
#define MH 8192
__global__ __launch_bounds__(256) void mlp_kernel(const unsigned short* __restrict__ specb,
                                                  const unsigned short* __restrict__ w1t,
                                                  const unsigned short* __restrict__ w2t,
                                                  const float* __restrict__ b1,
                                                  const float* __restrict__ b2,
                                                  const float* __restrict__ xin,
                                                  float* __restrict__ xout,
                                                  int rmul, int tmul) {
    __shared__ unsigned short mld[40960];
    const int seq = blockIdx.x, tid = threadIdx.x;
    const int q = tid >> 6, lane = tid & 63;
    const int m = lane & 15, g = lane >> 4;

    {
        const char* xsrc = (const char*)specb + (size_t)seq * 16384 + q * 1024 + lane * 16;
#pragma unroll
        for (int i = 0; i < 4; ++i)
            __builtin_amdgcn_global_load_lds((const void*)(xsrc + i * 4096),
                                             (void*)&mld[MX + i * 2048 + q * 512], 16, 0, 0);
    }
    bf16x8 bw1[4][2];
#pragma unroll
    for (int nt = 0; nt < 4; ++nt) {
        const int row = q * 64 + nt * 16 + m;
#pragma unroll
        for (int j = 0; j < 2; ++j)
            bw1[nt][j] = *(const bf16x8*)&w1t[row * 64 + (4 * j + g) * 8];
    }
    float b1v[4];
#pragma unroll
    for (int nt = 0; nt < 4; ++nt) b1v[nt] = b1[q * 64 + nt * 16 + m];
    __syncthreads();  // X staged

    f32x4 acc1[8][4];
#pragma unroll
    for (int mt = 0; mt < 8; ++mt)
#pragma unroll
        for (int nt = 0; nt < 4; ++nt) {
            f32x4 z = {b1v[nt], b1v[nt], b1v[nt], b1v[nt]};
            acc1[mt][nt] = z;
        }
#pragma unroll
    for (int mt = 0; mt < 8; ++mt) {
        const int row = mt * 16 + m;
        const int c0 = (g ^ (row & 7)) << 3;
        bf16x8 a0 = *(const bf16x8*)&mld[MX + row * 64 + c0];
        bf16x8 a1 = *(const bf16x8*)&mld[MX + row * 64 + (c0 ^ 32)];
#pragma unroll
        for (int nt = 0; nt < 4; ++nt) {
            acc1[mt][nt] = __builtin_amdgcn_mfma_f32_16x16x32_bf16(a0, bw1[nt][0], acc1[mt][nt], 0, 0, 0);
            acc1[mt][nt] = __builtin_amdgcn_mfma_f32_16x16x32_bf16(a1, bw1[nt][1], acc1[mt][nt], 0, 0, 0);
        }
    }

#pragma unroll
    for (int mt = 0; mt < 8; ++mt)
#pragma unroll
        for (int nt = 0; nt < 4; ++nt) {
            const int col = q * 64 + nt * 16 + m;
            const int c = col >> 3, jj = col & 7;
#pragma unroll
            for (int r = 0; r < 4; ++r) {
                const int row = mt * 16 + 4 * g + r;
                mld[MH + row * 256 + ((c ^ (row & 7)) << 3) + jj] = f2bf(gelu_fast(acc1[mt][nt][r]));
            }
        }
    __syncthreads();  // H complete

    float b2v[4];
#pragma unroll
    for (int nt = 0; nt < 4; ++nt) b2v[nt] = b2[nt * 16 + m];
    f32x4 acc2[2][4];
#pragma unroll
    for (int mt = 0; mt < 2; ++mt)
#pragma unroll
        for (int nt = 0; nt < 4; ++nt) {
            f32x4 z = {b2v[nt], b2v[nt], b2v[nt], b2v[nt]};
            acc2[mt][nt] = z;
        }
#pragma unroll
    for (int j = 0; j < 8; ++j) {
        bf16x8 aa[2];
#pragma unroll
        for (int mt = 0; mt < 2; ++mt) {
            const int row = (q + 4 * mt) * 16 + m;
            aa[mt] = *(const bf16x8*)&mld[MH + row * 256 + (((4 * j + g) ^ (row & 7)) << 3)];
        }
#pragma unroll
        for (int nt = 0; nt < 4; ++nt) {
            const int row = nt * 16 + m;
            bf16x8 bfr = *(const bf16x8*)&w2t[row * 256 + (4 * j + g) * 8];
            acc2[0][nt] = __builtin_amdgcn_mfma_f32_16x16x32_bf16(aa[0], bfr, acc2[0][nt], 0, 0, 0);
            acc2[1][nt] = __builtin_amdgcn_mfma_f32_16x16x32_bf16(aa[1], bfr, acc2[1][nt], 0, 0, 0);
        }
    }

    const int b = seq >> 7, rr = seq & 127;
    const size_t base = (size_t)b * 1048576 + (size_t)rr * (size_t)rmul;
#pragma unroll
    for (int mt = 0; mt < 2; ++mt)
#pragma unroll
        for (int nt = 0; nt < 4; ++nt)
#pragma unroll
            for (int r = 0; r < 4; ++r) {
                const int row = (q + 4 * mt) * 16 + 4 * g + r;
                const int col = nt * 16 + m;
                const size_t xi = base + (size_t)row * tmul + col;
                xout[xi] = xin[xi] + acc2[mt][nt][r];
            }
}

extern "C" void kernel_launch(void* const* d_in, const int* in_sizes, int n_in,
                              void* d_out, int out_size, void* d_ws, size_t ws_size,
                              hipStream_t stream) {
    const float* v         = (const float*)d_in[0];
    const float* gamma_row = (const float*)d_in[1];
    const float* beta_row  = (const float*)d_in[2];
    const float* gamma_col = (const float*)d_in[3];
    const float* beta_col  = (const float*)d_in[4];
    const float* mp_row    = (const float*)d_in[5];
    const float* mm_row    = (const float*)d_in[6];
    const float* mp_col    = (const float*)d_in[7];
    const float* mm_col    = (const float*)d_in[8];
    const float* w1_row    = (const float*)d_in[9];
    const float* b1_row    = (const float*)d_in[10];
    const float* w2_row    = (const float*)d_in[11];
    const float* b2_row    = (const float*)d_in[12];
    const float* w1_col    = (const float*)d_in[13];
    const float* b1_col    = (const float*)d_in[14];
    const float* w2_col    = (const float*)d_in[15];
    const float* b2_col    = (const float*)d_in[16];
    const float* phi_row   = (const float*)d_in[17];
    const float* phi_col   = (const float*)d_in[18];
    float* out = (float*)d_out;
    char* ws   = (char*)d_ws;

    unsigned short* yb   = (unsigned short*)ws;                      // 8 MB
    unsigned short* spcb = (unsigned short*)(ws + (8u << 20));       // 8 MB
    unsigned short* GcR  = (unsigned short*)(ws + (16u << 20));      // 1 MB
    unsigned short* GcC  = (unsigned short*)(ws + (17u << 20));      // 1 MB
    unsigned short* w1tR = (unsigned short*)(ws + (18u << 20));
    unsigned short* w2tR = (unsigned short*)(ws + (18u << 20) + 32768);
    unsigned short* w1tC = (unsigned short*)(ws + (18u << 20) + 65536);
    unsigned short* w2tC = (unsigned short*)(ws + (18u << 20) + 98304);

    init_kernel<<<36, 256, 0, stream>>>(phi_row, mp_row, mm_row, GcR,
                                        phi_col, mp_col, mm_col, GcC,
                                        w1_row, w1_col, w2_row, w2_col,
                                        w1tR, w1tC, w2tR, w2tC);

    // row pass: seq=(b,h), t=w (stride 64)
    ln_kernel<<<16384, 256, 0, stream>>>(v, yb, gamma_row, beta_row, 8192, 64);
    spec_kernel<<<512, 256, 0, stream>>>(yb, GcR, spcb);
    mlp_kernel<<<512, 256, 0, stream>>>(spcb, w1tR, w2tR, b1_row, b2_row, v, out, 8192, 64);

    // col pass: seq=(b,w), t=h (stride 128*64)
    ln_kernel<<<16384, 256, 0, stream>>>(out, yb, gamma_col, beta_col, 64, 8192);
    spec_kernel<<<512, 256, 0, stream>>>(yb, GcC, spcb);
    mlp_kernel<<<512, 256, 0, stream>>>(spcb, w1tC, w2tC, b1_col, b2_col, out, out, 64, 8192);
}

// Round 9
// 134.749 us; speedup vs baseline: 26.2895x; 1.1667x over previous
//
#include <hip/hip_runtime.h>

#define DD   64
#define HIDN 256
#define LLEN 128

typedef __attribute__((ext_vector_type(8))) short bf16x8;
typedef __attribute__((ext_vector_type(4))) float f32x4;

__device__ __forceinline__ float gelu_fast(float x) {
    const float u = 0.7978845608028654f * x * (1.0f + 0.044715f * x * x);
    return x * __builtin_amdgcn_rcpf(1.0f + __expf(-2.0f * u));
}

__device__ __forceinline__ unsigned short f2bf(float x) {
    union { float f; unsigned int u; } v; v.f = x;
    unsigned int r = v.u + 0x7FFF + ((v.u >> 16) & 1);
    return (unsigned short)(r >> 16);
}

// blocks 0..31: Gf fragment-major: Gf[s][frag=nt*2+kk][lane=g*16+m][8] holds
//   Gc[s][e=nt*16+m][d=kk*32+g*8 .. +8) as bf16 -> spec's B-loads are coalesced dwordx4.
// blocks 32..35: weight transposes.
__global__ __launch_bounds__(256) void init_kernel(const float* __restrict__ phi_r, const float* __restrict__ mp_r,
                                                   const float* __restrict__ mm_r, unsigned short* __restrict__ GcR,
                                                   const float* __restrict__ phi_c, const float* __restrict__ mp_c,
                                                   const float* __restrict__ mm_c, unsigned short* __restrict__ GcC,
                                                   const float* __restrict__ w1r, const float* __restrict__ w1c,
                                                   const float* __restrict__ w2r, const float* __restrict__ w2c,
                                                   unsigned short* __restrict__ w1tr, unsigned short* __restrict__ w1tc,
                                                   unsigned short* __restrict__ w2tr, unsigned short* __restrict__ w2tc) {
    const int bid = blockIdx.x, tid = threadIdx.x;
    if (bid < 32) {
        __shared__ float phis[2048];
        __shared__ unsigned short tile[4096];  // 16 s x 256 (e-major, d-minor)
        const int side = bid >> 4, chunk = bid & 15;
        const float* phi = side ? phi_c : phi_r;
        const float* mp  = side ? mp_c  : mp_r;
        const float* mm  = side ? mm_c  : mm_r;
        unsigned short* Gct = side ? GcC : GcR;
        const int i = chunk * 256 + tid;
        float pe[16], po[16];
#pragma unroll
        for (int k = 0; k < 16; ++k) {
            const float a = mp[k * 4096 + i];
            const float b = mm[k * 4096 + i];
            pe[k] = a + b; po[k] = a - b;
        }
        for (int j = tid; j < 2048; j += 256) phis[j] = phi[j];
        __syncthreads();
        const int e = tid & 63, dl = tid >> 6;
        const int d0 = chunk * 4;                    // this block owns d in [d0, d0+4)
        const int kk = d0 >> 5, g3 = (d0 >> 3) & 3, jl0 = d0 & 7;
        for (int s0 = 0; s0 < 128; s0 += 16) {
#pragma unroll
            for (int sb = 0; sb < 16; ++sb) {
                const int s = s0 + sb;
                const float* pk = &phis[s * 16];
                float acc = 0.0f;
                if (s & 1) {
#pragma unroll
                    for (int k = 0; k < 16; ++k) acc += pk[k] * po[k];
                } else {
#pragma unroll
                    for (int k = 0; k < 16; ++k) acc += pk[k] * pe[k];
                }
                tile[sb * 256 + e * 4 + dl] = f2bf(acc);
            }
            __syncthreads();
#pragma unroll
            for (int it = 0; it < 4; ++it) {
                const int p = it * 256 + tid;
                const int sb = p >> 6, ee = p & 63;
                uint2 v = *(const uint2*)&tile[sb * 256 + ee * 4];
                *(uint2*)&Gct[(size_t)(s0 + sb) * 4096 + (((ee >> 4) << 1) + kk) * 512 +
                              (g3 * 16 + (ee & 15)) * 8 + jl0] = v;
            }
            __syncthreads();
        }
    } else {
        const int b = bid - 32;
        if (b < 2) {
            const float* w1 = b ? w1c : w1r;
            unsigned short* dst = b ? w1tc : w1tr;
            const int n = tid;
            for (int k = 0; k < 64; ++k) dst[n * 64 + k] = f2bf(w1[k * 256 + n]);
        } else {
            const float* w2 = (b == 3) ? w2c : w2r;
            unsigned short* dst = (b == 3) ? w2tc : w2tr;
            const int n = tid & 63, kq = tid >> 6;
            for (int kk2 = 0; kk2 < 64; ++kk2) {
                const int k = kq * 64 + kk2;
                dst[n * 256 + k] = f2bf(w2[k * 64 + n]);
            }
        }
    }
}

// Fused pass: LN -> spec (reg-streaming B, no main-loop barriers) -> reduce -> MLP -> residual.
// 1 seq/block, 256 thr = 4 waves, grid 512 -> 2 blocks/CU (80 KB LDS).
// LDS byte regions (time-shared):
//   ys      [0, 18432)          (phase LN + spec loop)
//   scratch [18432, 67584)      (spec reduction, 3 x 16 KB)
//   X       [0, 16384)          (after spec loop; overwrites ys)
//   H       [16384, 81920)      (GEMM1 out; overwrites scratch)
#define SPEC_BODY(RR, BC, BN)                                                        \
    {                                                                                \
        const int s_ = 4 * (RR) + w;                                                 \
        if ((RR) < 31) {                                                             \
            const unsigned short* gq = Gf + (size_t)(s_ + 4) * 4096 + lane * 8;      \
            _Pragma("unroll")                                                        \
            for (int f = 0; f < 8; ++f) BN[f] = *(const bf16x8*)(gq + f * 512);      \
        }                                                                            \
        const int jmin_ = __builtin_amdgcn_readfirstlane(s_ >> 4);                   \
        _Pragma("unroll")                                                            \
        for (int j = 0; j < 8; ++j) {                                                \
            if (j >= jmin_) {                                                        \
                const int row_ = 16 + 16 * j - s_ + m;                               \
                const int c0_ = (g ^ (row_ & 7)) << 3;                               \
                const int ab_ = row_ * 64;                                           \
                bf16x8 a0_ = *(const bf16x8*)&lds[ab_ + c0_];                        \
                bf16x8 a1_ = *(const bf16x8*)&lds[ab_ + (c0_ ^ 32)];                 \
                _Pragma("unroll")                                                    \
                for (int nt = 0; nt < 4; ++nt) {                                     \
                    acc[j][nt] = __builtin_amdgcn_mfma_f32_16x16x32_bf16(a0_, BC[2 * nt], acc[j][nt], 0, 0, 0);     \
                    acc[j][nt] = __builtin_amdgcn_mfma_f32_16x16x32_bf16(a1_, BC[2 * nt + 1], acc[j][nt], 0, 0, 0); \
                }                                                                    \
            }                                                                        \
        }                                                                            \
    }

__global__ __launch_bounds__(256, 2) void fused_kernel(const float* __restrict__ xin,
                                                       float* __restrict__ xout,
                                                       const unsigned short* __restrict__ Gf,
                                                       const unsigned short* __restrict__ w1t,
                                                       const unsigned short* __restrict__ w2t,
                                                       const float* __restrict__ b1,
                                                       const float* __restrict__ b2,
                                                       const float* __restrict__ gamma,
                                                       const float* __restrict__ beta,
                                                       int rmul, int tmul) {
    __shared__ unsigned short lds[40960];  // 80 KB
    const int tid = threadIdx.x;
    const int w = tid >> 6, lane = tid & 63;
    const int seq = blockIdx.x;
    const int m = lane & 15, g = lane >> 4;
    const int bb = seq >> 7, rr = seq & 127;
    const size_t base = (size_t)bb * 1048576 + (size_t)rr * (size_t)rmul;

    // zero ys prefix rows 0..15 (bytes [0,2048))
    {
        uint2 z; z.x = 0u; z.y = 0u;
        *(uint2*)((char*)lds + tid * 8) = z;
    }

    // issue spec round-0 B load early (hides L2 latency under LN)
    bf16x8 Ba[8], Bb[8];
    {
        const unsigned short* gq = Gf + (size_t)w * 4096 + lane * 8;
#pragma unroll
        for (int f = 0; f < 8; ++f) Ba[f] = *(const bf16x8*)(gq + f * 512);
    }

    // ---- Phase 0: LayerNorm rows w*32 .. w*32+31 into swizzled ys ----
    {
        const float gl = gamma[lane], bl = beta[lane];
        float xv[32];
#pragma unroll
        for (int ti = 0; ti < 32; ++ti)
            xv[ti] = xin[base + (size_t)(w * 32 + ti) * tmul + lane];
#pragma unroll
        for (int ti = 0; ti < 32; ++ti) {
            const int t = w * 32 + ti;
            float s1 = xv[ti];
#pragma unroll
            for (int mm2 = 32; mm2 >= 1; mm2 >>= 1) s1 += __shfl_xor(s1, mm2);
            const float mu = s1 * (1.0f / 64.0f);
            const float dv = xv[ti] - mu;
            float s2 = dv * dv;
#pragma unroll
            for (int mm2 = 32; mm2 >= 1; mm2 >>= 1) s2 += __shfl_xor(s2, mm2);
            const float rstd = rsqrtf(s2 * (1.0f / 64.0f) + 1e-5f);
            const float nv = dv * rstd * gl + bl;
            lds[(t + 16) * 64 + (((lane >> 3) ^ (t & 7)) << 3) + (lane & 7)] = f2bf(nv);
        }
    }
    __syncthreads();  // ys complete

    // ---- Phase 1: spec main loop (no barriers) ----
    f32x4 acc[8][4];
#pragma unroll
    for (int j = 0; j < 8; ++j)
#pragma unroll
        for (int nt = 0; nt < 4; ++nt) {
            f32x4 z = {0.0f, 0.0f, 0.0f, 0.0f};
            acc[j][nt] = z;
        }
    for (int rp = 0; rp < 16; ++rp) {
        SPEC_BODY(2 * rp,     Ba, Bb);
        SPEC_BODY(2 * rp + 1, Bb, Ba);
    }

    // ---- Phase 2: reduction + X (bf16, swizzled) into LDS [0,16384) ----
    // dump1: waves 1,2,3 dump j=0..3
    if (w != 0) {
        char* pb = (char*)lds + 18432 + (w - 1) * 16384 + lane * 16;
#pragma unroll
        for (int j = 0; j < 4; ++j)
#pragma unroll
            for (int nt = 0; nt < 4; ++nt)
                *(f32x4*)(pb + (j * 4 + nt) * 1024) = acc[j][nt];
    }
    // weight fragment loads (global, overlap reduction)
    bf16x8 bw1[4][2];
    float b1v[4];
#pragma unroll
    for (int nt = 0; nt < 4; ++nt) {
        const int row = w * 64 + nt * 16 + m;
#pragma unroll
        for (int j = 0; j < 2; ++j)
            bw1[nt][j] = *(const bf16x8*)&w1t[row * 64 + (4 * j + g) * 8];
        b1v[nt] = b1[w * 64 + nt * 16 + m];
    }
    __syncthreads();
    if (w == 0) {
#pragma unroll
        for (int j = 0; j < 4; ++j)
#pragma unroll
            for (int nt = 0; nt < 4; ++nt)
#pragma unroll
                for (int sw = 0; sw < 3; ++sw)
                    acc[j][nt] += *(const f32x4*)((const char*)lds + 18432 + sw * 16384 +
                                                  (j * 4 + nt) * 1024 + lane * 16);
    }
    __syncthreads();  // w0 done reading scratch
    // dump2: waves 0,2,3 dump j=4..7; w0 writes X rows 0..63
    if (w != 1) {
        const int ri = (w == 0) ? 0 : (w - 1);
        char* pb = (char*)lds + 18432 + ri * 16384 + lane * 16;
#pragma unroll
        for (int j = 4; j < 8; ++j)
#pragma unroll
            for (int nt = 0; nt < 4; ++nt)
                *(f32x4*)(pb + ((j - 4) * 4 + nt) * 1024) = acc[j][nt];
    }
    if (w == 0) {
#pragma unroll
        for (int j = 0; j < 4; ++j)
#pragma unroll
            for (int nt = 0; nt < 4; ++nt)
#pragma unroll
                for (int rv = 0; rv < 4; ++rv) {
                    const int row = j * 16 + 4 * g + rv;
                    const int col = nt * 16 + m;
                    lds[row * 64 + (((col >> 3) ^ (row & 7)) << 3) + (col & 7)] = f2bf(acc[j][nt][rv]);
                }
    }
    __syncthreads();
    if (w == 1) {
#pragma unroll
        for (int j = 4; j < 8; ++j)
#pragma unroll
            for (int nt = 0; nt < 4; ++nt)
#pragma unroll
                for (int sw = 0; sw < 3; ++sw)
                    acc[j][nt] += *(const f32x4*)((const char*)lds + 18432 + sw * 16384 +
                                                  ((j - 4) * 4 + nt) * 1024 + lane * 16);
#pragma unroll
        for (int j = 4; j < 8; ++j)
#pragma unroll
            for (int nt = 0; nt < 4; ++nt)
#pragma unroll
                for (int rv = 0; rv < 4; ++rv) {
                    const int row = j * 16 + 4 * g + rv;
                    const int col = nt * 16 + m;
                    lds[row * 64 + (((col >> 3) ^ (row & 7)) << 3) + (col & 7)] = f2bf(acc[j][nt][rv]);
                }
    }
    __syncthreads();  // X complete (scratch dead)

    // ---- Phase 3: GEMM1  H = gelu(X @ W1 + b1); wave w owns hidden cols [64w, 64w+64) ----
    f32x4 acc1[8][4];
#pragma unroll
    for (int mt = 0; mt < 8; ++mt)
#pragma unroll
        for (int nt = 0; nt < 4; ++nt) {
            f32x4 z = {b1v[nt], b1v[nt], b1v[nt], b1v[nt]};
            acc1[mt][nt] = z;
        }
#pragma unroll
    for (int mt = 0; mt < 8; ++mt) {
        const int row = mt * 16 + m;
        const int c0 = (g ^ (row & 7)) << 3;
        bf16x8 a0 = *(const bf16x8*)&lds[row * 64 + c0];
        bf16x8 a1 = *(const bf16x8*)&lds[row * 64 + (c0 ^ 32)];
#pragma unroll
        for (int nt = 0; nt < 4; ++nt) {
            acc1[mt][nt] = __builtin_amdgcn_mfma_f32_16x16x32_bf16(a0, bw1[nt][0], acc1[mt][nt], 0, 0, 0);
            acc1[mt][nt] = __builtin_amdgcn_mfma_f32_16x16x32_bf16(a1, bw1[nt][1], acc1[mt][nt], 0, 0, 0);
        }
    }
    // gelu + H bf16 to LDS [16384,81920) (ush offset 8192, row stride 256 ush)
#pragma unroll
    for (int mt = 0; mt < 8; ++mt)
#pragma unroll
        for (int nt = 0; nt < 4; ++nt) {
            const int col = w * 64 + nt * 16 + m;
            const int c = col >> 3, jj = col & 7;
#pragma unroll
            for (int rv = 0; rv < 4; ++rv) {
                const int row = mt * 16 + 4 * g + rv;
                lds[8192 + row * 256 + ((c ^ (row & 7)) << 3) + jj] = f2bf(gelu_fast(acc1[mt][nt][rv]));
            }
        }
    __syncthreads();  // H complete

    // ---- Phase 4: GEMM2  O = H @ W2 + b2 + xin ----
    float b2v[4];
#pragma unroll
    for (int nt = 0; nt < 4; ++nt) b2v[nt] = b2[nt * 16 + m];
    f32x4 acc2[2][4];
#pragma unroll
    for (int mt = 0; mt < 2; ++mt)
#pragma unroll
        for (int nt = 0; nt < 4; ++nt) {
            f32x4 z = {b2v[nt], b2v[nt], b2v[nt], b2v[nt]};
            acc2[mt][nt] = z;
        }
#pragma unroll
    for (int j = 0; j < 8; ++j) {
        bf16x8 aa[2];
#pragma unroll
        for (int mt = 0; mt < 2; ++mt) {
            const int row = (w + 4 * mt) * 16 + m;
            aa[mt] = *(const bf16x8*)&lds[8192 + row * 256 + (((4 * j + g) ^ (row & 7)) << 3)];
        }
#pragma unroll
        for (int nt = 0; nt < 4; ++nt) {
            const int row = nt * 16 + m;
            bf16x8 bfr = *(const bf16x8*)&w2t[row * 256 + (4 * j + g) * 8];
            acc2[0][nt] = __builtin_amdgcn_mfma_f32_16x16x32_bf16(aa[0], bfr, acc2[0][nt], 0, 0, 0);
            acc2[1][nt] = __builtin_amdgcn_mfma_f32_16x16x32_bf16(aa[1], bfr, acc2[1][nt], 0, 0, 0);
        }
    }
#pragma unroll
    for (int mt = 0; mt < 2; ++mt)
#pragma unroll
        for (int nt = 0; nt < 4; ++nt)
#pragma unroll
            for (int rv = 0; rv < 4; ++rv) {
                const int row = (w + 4 * mt) * 16 + 4 * g + rv;
                const int col = nt * 16 + m;
                const size_t xi = base + (size_t)row * tmul + col;
                xout[xi] = xin[xi] + acc2[mt][nt][rv];
            }
}

extern "C" void kernel_launch(void* const* d_in, const int* in_sizes, int n_in,
                              void* d_out, int out_size, void* d_ws, size_t ws_size,
                              hipStream_t stream) {
    const float* v         = (const float*)d_in[0];
    const float* gamma_row = (const float*)d_in[1];
    const float* beta_row  = (const float*)d_in[2];
    const float* gamma_col = (const float*)d_in[3];
    const float* beta_col  = (const float*)d_in[4];
    const float* mp_row    = (const float*)d_in[5];
    const float* mm_row    = (const float*)d_in[6];
    const float* mp_col    = (const float*)d_in[7];
    const float* mm_col    = (const float*)d_in[8];
    const float* w1_row    = (const float*)d_in[9];
    const float* b1_row    = (const float*)d_in[10];
    const float* w2_row    = (const float*)d_in[11];
    const float* b2_row    = (const float*)d_in[12];
    const float* w1_col    = (const float*)d_in[13];
    const float* b1_col    = (const float*)d_in[14];
    const float* w2_col    = (const float*)d_in[15];
    const float* b2_col    = (const float*)d_in[16];
    const float* phi_row   = (const float*)d_in[17];
    const float* phi_col   = (const float*)d_in[18];
    float* out = (float*)d_out;
    char* ws   = (char*)d_ws;

    unsigned short* GfR  = (unsigned short*)ws;                      // 1 MB
    unsigned short* GfC  = (unsigned short*)(ws + (1u << 20));       // 1 MB
    unsigned short* w1tR = (unsigned short*)(ws + (2u << 20));
    unsigned short* w2tR = (unsigned short*)(ws + (2u << 20) + 32768);
    unsigned short* w1tC = (unsigned short*)(ws + (2u << 20) + 65536);
    unsigned short* w2tC = (unsigned short*)(ws + (2u << 20) + 98304);

    init_kernel<<<36, 256, 0, stream>>>(phi_row, mp_row, mm_row, GfR,
                                        phi_col, mp_col, mm_col, GfC,
                                        w1_row, w1_col, w2_row, w2_col,
                                        w1tR, w1tC, w2tR, w2tC);

    // row pass: seq=(b,h), rmul=8192 (h stride), tmul=64 (w stride)
    fused_kernel<<<512, 256, 0, stream>>>(v, out, GfR, w1tR, w2tR, b1_row, b2_row,
                                          gamma_row, beta_row, 8192, 64);
    // col pass: seq=(b,w), rmul=64 (w stride), tmul=8192 (h stride)
    fused_kernel<<<512, 256, 0, stream>>>(out, out, GfC, w1tC, w2tC, b1_col, b2_col,
                                          gamma_col, beta_col, 64, 8192);
}